// Round 1
// 2009.840 us; speedup vs baseline: 1.6917x; 1.6917x over previous
//
#include <hip/hip_runtime.h>
#include <hip/hip_bf16.h>
#include <math.h>

#define EE   512
#define HJ   1024
#define VV   32000
#define BB   32
#define SS   48
#define TT   48

typedef float f32x4 __attribute__((ext_vector_type(4)));
typedef __bf16 bf16x8 __attribute__((ext_vector_type(8)));
typedef __bf16 bf16x4 __attribute__((ext_vector_type(4)));

// ---------------------------------------------------------------- coherent access helpers
// Cross-XCD coherence is done per-access (sc0 sc1 = write-through / read-from MALL),
// NOT with agent fences. This keeps read-only data (senc, pre, weights) resident in
// each XCD's L2 across grid barriers -- the old __threadfence() pair per barrier
// emitted buffer_wbl2 + buffer_inv, flushing/invalidating L2 ~32x per XCD per barrier.
__device__ __forceinline__ bf16x8 ld_coh_x8(const __bf16* p) {
  bf16x8 r;
  asm volatile("global_load_dwordx4 %0, %1, off sc0 sc1" : "=v"(r) : "v"(p) : "memory");
  return r;
}
__device__ __forceinline__ void st_coh_b16(__bf16* p, __bf16 v) {
  unsigned int w = __builtin_bit_cast(unsigned short, v);
  asm volatile("global_store_short %0, %1, off sc0 sc1" :: "v"(p), "v"(w) : "memory");
}

// ---------------------------------------------------------------- grid barrier
// Decentralized: one flag per block on its own 64B line. Protocol:
//   - all cross-block data is written with sc0sc1 (write-through to MALL)
//   - __syncthreads() drains vmcnt(0) for every thread -> all data at MALL
//   - tid0 publishes its flag (relaxed agent atomic = sc0sc1 store)
//   - thread i polls block i's flag (relaxed agent atomic = MALL read)
//   - readers use sc0sc1 loads for cross-block data -> no stale-L2 hazard
// => NO buffer_wbl2, NO buffer_inv anywhere in the loop.
// grid must be 256 blocks of 256 threads (thread i polls block i's flag).
__device__ __forceinline__ void gbar(int* flags, int step) {
  asm volatile("s_waitcnt vmcnt(0)" ::: "memory");  // belt&suspenders (syncthreads also drains)
  __syncthreads();
  if (threadIdx.x == 0)
    __hip_atomic_store(flags + blockIdx.x * 16, step, __ATOMIC_RELAXED,
                       __HIP_MEMORY_SCOPE_AGENT);
  while (__hip_atomic_load(flags + threadIdx.x * 16, __ATOMIC_RELAXED,
                           __HIP_MEMORY_SCOPE_AGENT) < step)
    __builtin_amdgcn_s_sleep(1);
  __syncthreads();                       // all 256 flags observed by this block
}

// ---------------------------------------------------------------- embeddings
__global__ void embed_src_kernel(const float* __restrict__ enc_embed,
                                 const int* __restrict__ src_tokens,
                                 const int* __restrict__ src_lengths,
                                 __bf16* __restrict__ emb, __bf16* __restrict__ embR) {
  int idx = blockIdx.x * 256 + threadIdx.x;
  if (idx >= BB * SS * EE) return;
  int e = idx & (EE - 1);
  int bs = idx >> 9;
  int b = bs / SS, s = bs % SS;
  int tok = src_tokens[b * SS + s];
  emb[idx] = (__bf16)enc_embed[(size_t)tok * EE + e];
  int len = src_lengths[b];
  int rs = len - 1 - s; if (rs < 0) rs = 0;
  int tokr = src_tokens[b * SS + rs];
  embR[idx] = (__bf16)enc_embed[(size_t)tokr * EE + e];
}

__global__ void embed_tgt_kernel(const float* __restrict__ dec_embed,
                                 const int* __restrict__ tgt_tokens,
                                 __bf16* __restrict__ demb) {
  int idx = blockIdx.x * 256 + threadIdx.x;
  if (idx >= BB * TT * EE) return;
  int e = idx & (EE - 1);
  int bt = idx >> 9;
  int b = bt / TT, t = bt % TT;
  int tok = tgt_tokens[b * (TT + 1) + t];
  demb[idx] = (__bf16)dec_embed[(size_t)tok * EE + e];
}

// ---------------------------------------------------------------- converts
__global__ void f2bf_kernel(const float* __restrict__ src, __bf16* __restrict__ dst, int n4) {
  int i = blockIdx.x * 256 + threadIdx.x;
  if (i >= n4) return;
  float4 v = ((const float4*)src)[i];
  bf16x4 p = {(__bf16)v.x, (__bf16)v.y, (__bf16)v.z, (__bf16)v.w};
  ((bf16x4*)dst)[i] = p;
}

__global__ void f2bf_slice_kernel(const float* __restrict__ src, __bf16* __restrict__ dst,
                                  int rows, int cols, int ld, int c0) {
  int idx = blockIdx.x * 256 + threadIdx.x;
  if (idx >= rows * cols) return;
  int r = idx / cols, cc = idx % cols;
  dst[idx] = (__bf16)src[(size_t)r * ld + c0 + cc];
}

// Wd[r][k]: k<1024 -> dWih[r][k] (wa cols), else dWhh[r][k-1024]
__global__ void wdec_build_kernel(const float* __restrict__ dWih, const float* __restrict__ dWhh,
                                  __bf16* __restrict__ Wd) {
  int idx = blockIdx.x * 256 + threadIdx.x;
  if (idx >= 4096 * 2048) return;
  int r = idx >> 11, k = idx & 2047;
  float v = (k < 1024) ? dWih[(size_t)r * 1536 + k] : dWhh[(size_t)r * 1024 + (k - 1024)];
  Wd[idx] = (__bf16)v;
}

// ---------------------------------------------------------------- bf16 MFMA GEMM (NT)
__global__ __launch_bounds__(256) void gemm_bf16_kernel(
    const __bf16* __restrict__ A, const __bf16* __restrict__ Bm,
    const float* __restrict__ bias1, const float* __restrict__ bias2,
    float* __restrict__ C, int K, int N) {
  const int m0 = blockIdx.x * 128;
  const int n0 = blockIdx.y * 128;
  __shared__ __bf16 As[128 * 40];
  __shared__ __bf16 Bs[128 * 40];
  const int tid = threadIdx.x;
  const int lane = tid & 63, wave = tid >> 6;
  const int wm = (wave >> 1) * 64, wn = (wave & 1) * 64;
  const f32x4 zero = {0.f, 0.f, 0.f, 0.f};
  f32x4 acc[4][4];
  for (int i = 0; i < 4; i++) for (int j = 0; j < 4; j++) acc[i][j] = zero;
  const int r = tid >> 2, seg = tid & 3;
  const int mr = lane & 15, q8 = (lane >> 4) * 8;
  for (int k0 = 0; k0 < K; k0 += 32) {
    *(float4*)&As[r * 40 + seg * 8]        = *(const float4*)&A[(size_t)(m0 + r) * K + k0 + seg * 8];
    *(float4*)&As[(r + 64) * 40 + seg * 8] = *(const float4*)&A[(size_t)(m0 + r + 64) * K + k0 + seg * 8];
    *(float4*)&Bs[r * 40 + seg * 8]        = *(const float4*)&Bm[(size_t)(n0 + r) * K + k0 + seg * 8];
    *(float4*)&Bs[(r + 64) * 40 + seg * 8] = *(const float4*)&Bm[(size_t)(n0 + r + 64) * K + k0 + seg * 8];
    __syncthreads();
    bf16x8 af[4], bfr[4];
    for (int i = 0; i < 4; i++) af[i]  = *(const bf16x8*)&As[(wm + i * 16 + mr) * 40 + q8];
    for (int i = 0; i < 4; i++) bfr[i] = *(const bf16x8*)&Bs[(wn + i * 16 + mr) * 40 + q8];
    for (int i = 0; i < 4; i++)
      for (int j = 0; j < 4; j++)
        acc[i][j] = __builtin_amdgcn_mfma_f32_16x16x32_bf16(af[i], bfr[j], acc[i][j], 0, 0, 0);
    __syncthreads();
  }
  const int col = lane & 15, q = lane >> 4;
  for (int i = 0; i < 4; i++) {
    int rowg = m0 + wm + i * 16 + q * 4;
    for (int j = 0; j < 4; j++) {
      int cg = n0 + wn + j * 16 + col;
      float bb = bias1[cg] + bias2[cg];
      for (int rr = 0; rr < 4; rr++)
        C[(size_t)(rowg + rr) * N + cg] = acc[i][j][rr] + bb;
    }
  }
}

// ---------------------------------------------------------------- logits MFMA + exp-sum epilogue
// BF=1: B is pre-converted bf16 [32000][2048]. BF=0: B is fp32, convert in staging.
template <int BF>
__global__ __launch_bounds__(256) void logits_kernel(
    const __bf16* __restrict__ A, const void* __restrict__ Braw,
    const float* __restrict__ Wsb, float* __restrict__ rowsum) {
  const int m0 = blockIdx.x * 128;
  const int n0 = blockIdx.y * 128;
  __shared__ __bf16 As[128 * 40];
  __shared__ __bf16 Bs[128 * 40];
  const int tid = threadIdx.x;
  const int lane = tid & 63, wave = tid >> 6;
  const int wm = (wave >> 1) * 64, wn = (wave & 1) * 64;
  const f32x4 zero = {0.f, 0.f, 0.f, 0.f};
  f32x4 acc[4][4];
  for (int i = 0; i < 4; i++) for (int j = 0; j < 4; j++) acc[i][j] = zero;
  const int r = tid >> 2, seg = tid & 3;
  const int rowb = tid >> 1, koff = (tid & 1) * 16;
  const int mr = lane & 15, q8 = (lane >> 4) * 8;
  for (int k0 = 0; k0 < 2048; k0 += 32) {
    *(float4*)&As[r * 40 + seg * 8]        = *(const float4*)&A[(size_t)(m0 + r) * 2048 + k0 + seg * 8];
    *(float4*)&As[(r + 64) * 40 + seg * 8] = *(const float4*)&A[(size_t)(m0 + r + 64) * 2048 + k0 + seg * 8];
    if (BF) {
      const __bf16* Bb = (const __bf16*)Braw;
      *(float4*)&Bs[r * 40 + seg * 8]        = *(const float4*)&Bb[(size_t)(n0 + r) * 2048 + k0 + seg * 8];
      *(float4*)&Bs[(r + 64) * 40 + seg * 8] = *(const float4*)&Bb[(size_t)(n0 + r + 64) * 2048 + k0 + seg * 8];
    } else {
      const float* gb = (const float*)Braw + (size_t)(n0 + rowb) * 2048 + k0 + koff;
      float4 v0 = *(const float4*)(gb);
      float4 v1 = *(const float4*)(gb + 4);
      float4 v2 = *(const float4*)(gb + 8);
      float4 v3 = *(const float4*)(gb + 12);
      bf16x8 p0 = {(__bf16)v0.x,(__bf16)v0.y,(__bf16)v0.z,(__bf16)v0.w,
                   (__bf16)v1.x,(__bf16)v1.y,(__bf16)v1.z,(__bf16)v1.w};
      bf16x8 p1 = {(__bf16)v2.x,(__bf16)v2.y,(__bf16)v2.z,(__bf16)v2.w,
                   (__bf16)v3.x,(__bf16)v3.y,(__bf16)v3.z,(__bf16)v3.w};
      *(bf16x8*)&Bs[rowb * 40 + koff]     = p0;
      *(bf16x8*)&Bs[rowb * 40 + koff + 8] = p1;
    }
    __syncthreads();
    bf16x8 af[4], bfr[4];
    for (int i = 0; i < 4; i++) af[i]  = *(const bf16x8*)&As[(wm + i * 16 + mr) * 40 + q8];
    for (int i = 0; i < 4; i++) bfr[i] = *(const bf16x8*)&Bs[(wn + i * 16 + mr) * 40 + q8];
    for (int i = 0; i < 4; i++)
      for (int j = 0; j < 4; j++)
        acc[i][j] = __builtin_amdgcn_mfma_f32_16x16x32_bf16(af[i], bfr[j], acc[i][j], 0, 0, 0);
    __syncthreads();
  }
  const int col = lane & 15, q = lane >> 4;
  for (int i = 0; i < 4; i++) {
    float s0 = 0, s1 = 0, s2 = 0, s3 = 0;
    for (int j = 0; j < 4; j++) {
      int cg = n0 + wn + j * 16 + col;
      float bb = Wsb[cg];
      s0 += expf(acc[i][j][0] + bb);
      s1 += expf(acc[i][j][1] + bb);
      s2 += expf(acc[i][j][2] + bb);
      s3 += expf(acc[i][j][3] + bb);
    }
    for (int off = 1; off < 16; off <<= 1) {
      s0 += __shfl_xor(s0, off, 64);
      s1 += __shfl_xor(s1, off, 64);
      s2 += __shfl_xor(s2, off, 64);
      s3 += __shfl_xor(s3, off, 64);
    }
    if (col == 0) {
      int rowg = m0 + wm + i * 16 + q * 4;
      atomicAdd(&rowsum[rowg],     s0);
      atomicAdd(&rowsum[rowg + 1], s1);
      atomicAdd(&rowsum[rowg + 2], s2);
      atomicAdd(&rowsum[rowg + 3], s3);
    }
  }
}

// ---------------------------------------------------------------- persistent encoder
__global__ __launch_bounds__(256) void enc_persistent(
    const __bf16* __restrict__ Wenc,   // [2][2048][512] bf16
    const float* __restrict__ xg,      // [2][1536][2048]
    const int* __restrict__ lens,
    __bf16* __restrict__ g_h,          // [2dir][2buf][32*512] bf16 (buf0 zeroed)
    float* __restrict__ cenc,          // [2][32][512]
    __bf16* __restrict__ ob,           // [2][1536][512] masked outputs
    int* __restrict__ flags) {
  const int bk = blockIdx.x;
  const int dir = bk >> 7;
  const int u0 = (bk & 127) * 4;
  const int tid = threadIdx.x;
  const int lane = tid & 63, wave = tid >> 6;
  __shared__ __bf16 Wl[16 * 520];
  __shared__ float gsc[4 * 512];
  __shared__ float cl[128], hloc[128];
  {
    int row = tid >> 4, t16 = tid & 15;
    int g = row >> 2, du = row & 3;
    const __bf16* src = Wenc + ((size_t)dir * 2048 + g * 512 + u0 + du) * 512;
    for (int c = t16 * 32, e = t16 * 32 + 32; c < e; c += 8)
      *(bf16x8*)&Wl[row * 520 + c] = *(const bf16x8*)&src[c];
  }
  if (tid < 128) { cl[tid] = 0.f; hloc[tid] = 0.f; }
  __syncthreads();
  __bf16* ghd = g_h + dir * 32768;
  __bf16* obd = ob + (size_t)dir * (1536 * 512);
  const float* xgd = xg + (size_t)dir * 1536 * 2048;
  const int nr = lane & 15, q8 = (lane >> 4) * 8;
  for (int t = 0; t < SS; t++) {
    const int cur = t & 1;
    const __bf16* hc = ghd + cur * 16384;
    __bf16* hnx = ghd + (cur ^ 1) * 16384;
    float xv[4];
    if (tid < 128) {
      int b = tid >> 2, du = tid & 3;
#pragma unroll
      for (int g = 0; g < 4; g++)
        xv[g] = xgd[((size_t)b * SS + t) * 2048 + g * 512 + u0 + du];
    }
    f32x4 acc0 = {0.f,0.f,0.f,0.f}, acc1 = {0.f,0.f,0.f,0.f};
    const int kb = wave * 128;
    // burst-issue coherent loads of the remotely-written h buffer, then one wait
    bf16x8 a0[4], a1[4];
#pragma unroll
    for (int ks = 0; ks < 4; ks++) {
      int k0 = kb + ks * 32;
      a0[ks] = ld_coh_x8(&hc[nr * 512 + k0 + q8]);
      a1[ks] = ld_coh_x8(&hc[(nr + 16) * 512 + k0 + q8]);
    }
    asm volatile("s_waitcnt vmcnt(0)" ::: "memory");
    __builtin_amdgcn_sched_barrier(0);
#pragma unroll
    for (int ks = 0; ks < 4; ks++) {
      int k0 = kb + ks * 32;
      bf16x8 bf_ = *(const bf16x8*)&Wl[nr * 520 + k0 + q8];
      acc0 = __builtin_amdgcn_mfma_f32_16x16x32_bf16(a0[ks], bf_, acc0, 0, 0, 0);
      acc1 = __builtin_amdgcn_mfma_f32_16x16x32_bf16(a1[ks], bf_, acc1, 0, 0, 0);
    }
#pragma unroll
    for (int rg = 0; rg < 4; rg++) {
      int m = (lane >> 4) * 4 + rg;
      gsc[wave * 512 + m * 16 + nr]       = acc0[rg];
      gsc[wave * 512 + 256 + m * 16 + nr] = acc1[rg];
    }
    __syncthreads();
    if (tid < 128) {
      int b = tid >> 2, du = tid & 3;
      float gt[4];
#pragma unroll
      for (int g = 0; g < 4; g++) {
        int base = (b >> 4) * 256 + (b & 15) * 16 + g * 4 + du;
        gt[g] = xv[g] + gsc[base] + gsc[512 + base] + gsc[1024 + base] + gsc[1536 + base];
      }
      bool m_ = t < lens[b];
      float cold = cl[tid], hold = hloc[tid];
      float si = 1.f / (1.f + __expf(-gt[0])), sf = 1.f / (1.f + __expf(-gt[1]));
      float so = 1.f / (1.f + __expf(-gt[3]));
      float cn = sf * cold + si * tanhf(gt[2]);
      float hv = so * tanhf(cn);
      float cne = m_ ? cn : cold;
      float hne = m_ ? hv : hold;
      cl[tid] = cne; hloc[tid] = hne;
      st_coh_b16(&hnx[b * 512 + u0 + du], (__bf16)hne);   // cross-block: coherent
      obd[((size_t)b * SS + t) * 512 + u0 + du] = m_ ? (__bf16)hv : (__bf16)0.f;  // read post-kernel: plain
    }
    gbar(flags, t + 1);
  }
  if (tid < 128) {
    int b = tid >> 2, du = tid & 3;
    cenc[(size_t)dir * 16384 + b * 512 + u0 + du] = cl[tid];
  }
}

// ---------------------------------------------------------------- compose
__global__ void compose_kernel(const __bf16* __restrict__ ob, const __bf16* __restrict__ g_h,
                               const float* __restrict__ cenc, const int* __restrict__ lens,
                               __bf16* __restrict__ senc, __bf16* __restrict__ g_x0,
                               float* __restrict__ cdec) {
  int idx = blockIdx.x * 256 + threadIdx.x;
  const int N1 = 1536 * 1024;
  if (idx < N1) {
    int u = idx & 1023, bs = idx >> 10, b = bs / SS, s = bs - b * SS;
    __bf16 v;
    if (u < 512) v = ob[(size_t)bs * 512 + u];
    else {
      int len = lens[b];
      if (s < len) {
        int rs = len - 1 - s;
        v = ob[(size_t)(1536 * 512) + ((size_t)b * SS + rs) * 512 + (u - 512)];
      } else v = (__bf16)0.f;
    }
    senc[idx] = v;
  } else if (idx < N1 + 32 * 2048) {
    int k = idx - N1;
    int b = k >> 11, u = k & 2047;
    __bf16 v = (__bf16)0.f;
    if (u >= 1024) {
      int uu = u - 1024;
      v = (uu < 512) ? g_h[b * 512 + uu] : g_h[32768 + b * 512 + (uu - 512)];
    }
    g_x0[k] = v;
  } else if (idx < N1 + 32 * 2048 + 32 * 1024) {
    int k = idx - N1 - 32 * 2048;
    int b = k >> 10, u = k & 1023;
    cdec[k] = (u < 512) ? cenc[b * 512 + u] : cenc[16384 + b * 512 + (u - 512)];
  }
}

// ---------------------------------------------------------------- persistent decoder
__global__ __launch_bounds__(256) void dec_persistent(
    const __bf16* __restrict__ Wd,     // [4096][2048] bf16
    const float* __restrict__ pre,     // [1536][4096]
    const __bf16* __restrict__ senc,   // [1536][1024] bf16
    const int* __restrict__ lens,
    const float* __restrict__ cdec,    // [32][1024]
    __bf16* __restrict__ g_x,          // [2][32][2048] bf16 (buf0 = wa0|h0)
    __bf16* __restrict__ outs,         // [1536][2048] bf16
    int* __restrict__ flags) {
  const int bk = blockIdx.x;
  const int u0 = bk * 4;
  const int tid = threadIdx.x, lane = tid & 63, wave = tid >> 6;
  __shared__ __bf16 Wl[16 * 2056];
  __shared__ float gsc[4 * 512];
  __shared__ float cl[128];
  __shared__ float asm_l[48];
  {
    int row = tid >> 4, t16 = tid & 15;
    int g = row >> 2, du = row & 3;
    const __bf16* src = Wd + (size_t)(g * 1024 + u0 + du) * 2048;
    for (int c = t16 * 128, e = t16 * 128 + 128; c < e; c += 8)
      *(bf16x8*)&Wl[row * 2056 + c] = *(const bf16x8*)&src[c];
  }
  if (tid < 128) cl[tid] = cdec[(tid >> 2) * 1024 + u0 + (tid & 3)];
  __syncthreads();
  const int nr = lane & 15, q8 = (lane >> 4) * 8;
  const int bC = bk >> 3, j0 = (bk & 7) * 128;
  for (int t = 0; t < TT; t++) {
    const int cur = t & 1;
    const __bf16* xc = g_x + cur * (32 * 2048);
    __bf16* xn = g_x + (cur ^ 1) * (32 * 2048);
    float xv[4];
    if (tid < 128) {
      int b = tid >> 2, du = tid & 3;
#pragma unroll
      for (int g = 0; g < 4; g++)
        xv[g] = pre[((size_t)b * TT + t) * 4096 + g * 1024 + u0 + du];
    }
    f32x4 acc0 = {0.f,0.f,0.f,0.f}, acc1 = {0.f,0.f,0.f,0.f};
    const int kb = wave * 512;
    // burst-issue all 32 coherent loads of the remotely-written x buffer, one wait
    bf16x8 a0[16], a1[16];
#pragma unroll
    for (int ks = 0; ks < 16; ks++) {
      int k0 = kb + ks * 32;
      a0[ks] = ld_coh_x8(&xc[nr * 2048 + k0 + q8]);
      a1[ks] = ld_coh_x8(&xc[(nr + 16) * 2048 + k0 + q8]);
    }
    asm volatile("s_waitcnt vmcnt(0)" ::: "memory");
    __builtin_amdgcn_sched_barrier(0);
#pragma unroll
    for (int ks = 0; ks < 16; ks++) {
      int k0 = kb + ks * 32;
      bf16x8 bf_ = *(const bf16x8*)&Wl[nr * 2056 + k0 + q8];
      acc0 = __builtin_amdgcn_mfma_f32_16x16x32_bf16(a0[ks], bf_, acc0, 0, 0, 0);
      acc1 = __builtin_amdgcn_mfma_f32_16x16x32_bf16(a1[ks], bf_, acc1, 0, 0, 0);
    }
#pragma unroll
    for (int rg = 0; rg < 4; rg++) {
      int m = (lane >> 4) * 4 + rg;
      gsc[wave * 512 + m * 16 + nr]       = acc0[rg];
      gsc[wave * 512 + 256 + m * 16 + nr] = acc1[rg];
    }
    __syncthreads();
    if (tid < 128) {
      int b = tid >> 2, du = tid & 3;
      float gt[4];
#pragma unroll
      for (int g = 0; g < 4; g++) {
        int base = (b >> 4) * 256 + (b & 15) * 16 + g * 4 + du;
        gt[g] = xv[g] + gsc[base] + gsc[512 + base] + gsc[1024 + base] + gsc[1536 + base];
      }
      float cold = cl[tid];
      float si = 1.f / (1.f + __expf(-gt[0])), sf = 1.f / (1.f + __expf(-gt[1]));
      float so = 1.f / (1.f + __expf(-gt[3]));
      float cn = sf * cold + si * tanhf(gt[2]);
      float hv = so * tanhf(cn);
      cl[tid] = cn;
      __bf16 hb = (__bf16)hv;
      st_coh_b16(&xn[b * 2048 + 1024 + u0 + du], hb);     // cross-block: coherent
      outs[((size_t)b * TT + t) * 2048 + 1024 + u0 + du] = hb;  // read post-kernel: plain
    }
    gbar(flags, 2 * t + 1);            // h(t) visible everywhere
    // ---- attention: each block computes align+softmax for its bC (8x redundant)
    {
      int len = lens[bC];
      const __bf16* hh = xn + bC * 2048 + 1024;
      bf16x8 h0 = ld_coh_x8(&hh[lane * 16]);              // remotely written -> coherent
      bf16x8 h1 = ld_coh_x8(&hh[lane * 16 + 8]);
      asm volatile("s_waitcnt vmcnt(0)" ::: "memory");
      __builtin_amdgcn_sched_barrier(0);
      float hf[16];
#pragma unroll
      for (int i = 0; i < 8; i++) { hf[i] = (float)h0[i]; hf[8 + i] = (float)h1[i]; }
      for (int si = 0; si < 12; si++) {
        int s = wave * 12 + si;
        if (s >= len) { if (lane == 0) asm_l[s] = -1e30f; continue; }
        const __bf16* se = senc + ((size_t)bC * SS + s) * 1024;   // read-only: plain (L2-hot now)
        bf16x8 s0 = *(const bf16x8*)&se[lane * 16];
        bf16x8 s1 = *(const bf16x8*)&se[lane * 16 + 8];
        float p = 0.f;
#pragma unroll
        for (int i = 0; i < 8; i++) p += (float)s0[i] * hf[i] + (float)s1[i] * hf[8 + i];
#pragma unroll
        for (int off = 32; off > 0; off >>= 1) p += __shfl_xor(p, off, 64);
        if (lane == 0) asm_l[s] = p;
      }
      __syncthreads();
      if (wave == 0) {
        float a = (lane < SS) ? asm_l[lane] : -1e30f;
        float mx = a;
#pragma unroll
        for (int off = 32; off > 0; off >>= 1) mx = fmaxf(mx, __shfl_xor(mx, off, 64));
        float p = (lane < SS) ? __expf(a - mx) : 0.f;
        float sm = p;
#pragma unroll
        for (int off = 32; off > 0; off >>= 1) sm += __shfl_xor(sm, off, 64);
        if (lane < SS) asm_l[lane] = p / sm;
      }
      __syncthreads();
      if (tid < 128) {
        int j = j0 + tid;
        const __bf16* sb = senc + (size_t)bC * SS * 1024 + j;     // read-only: plain
        float w = 0.f;
#pragma unroll 8
        for (int s = 0; s < SS; s++) w += asm_l[s] * (float)sb[s * 1024];
        __bf16 wb = (__bf16)w;
        st_coh_b16(&xn[bC * 2048 + j], wb);               // cross-block: coherent
        outs[((size_t)bC * TT + t) * 2048 + j] = wb;      // read post-kernel: plain
      }
    }
    gbar(flags, 2 * t + 2);            // wa(t) visible everywhere
  }
}

// ---------------------------------------------------------------- target logit per row
__global__ __launch_bounds__(256) void tgt_logit_kernel(
    const __bf16* __restrict__ outs_bf, const float* __restrict__ WsW,
    const float* __restrict__ Wsb, const int* __restrict__ tgt_tokens,
    float* __restrict__ tlogit) {
  const int r = blockIdx.x;
  const int b = r / TT, t = r % TT;
  const int tgt = tgt_tokens[b * (TT + 1) + t + 1];
  const __bf16* a = outs_bf + (size_t)r * 2048;
  const float* w = WsW + (size_t)tgt * 2048;
  const int tid = threadIdx.x;
  float p = 0;
  for (int k = tid; k < 2048; k += 256) p += (float)a[k] * w[k];
  for (int off = 32; off > 0; off >>= 1) p += __shfl_down(p, off, 64);
  __shared__ float red[4];
  if ((tid & 63) == 0) red[tid >> 6] = p;
  __syncthreads();
  if (tid == 0) tlogit[r] = red[0] + red[1] + red[2] + red[3] + Wsb[tgt];
}

// ---------------------------------------------------------------- final reduce
__global__ void final_kernel(const float* __restrict__ rowsum, const float* __restrict__ tlogit,
                             const int* __restrict__ tgt_tokens, float* __restrict__ out) {
  const int tid = threadIdx.x;
  float s = 0;
  for (int r = tid; r < BB * TT; r += 256) {
    int b = r / TT, t = r % TT;
    int tgt = tgt_tokens[b * (TT + 1) + t + 1];
    if (tgt != 0) s += logf(rowsum[r]) - tlogit[r];
  }
  for (int off = 32; off > 0; off >>= 1) s += __shfl_down(s, off, 64);
  __shared__ float red[4];
  if ((tid & 63) == 0) red[tid >> 6] = s;
  __syncthreads();
  if (tid == 0) out[0] = red[0] + red[1] + red[2] + red[3];
}

// ================================================================ host
extern "C" void kernel_launch(void* const* d_in, const int* in_sizes, int n_in,
                              void* d_out, int out_size, void* d_ws, size_t ws_size,
                              hipStream_t stream) {
  const float* enc_embed = (const float*)d_in[0];
  const float* dec_embed = (const float*)d_in[1];
  const float* eWih_f = (const float*)d_in[2];
  const float* eWhh_f = (const float*)d_in[3];
  const float* ebih_f = (const float*)d_in[4];
  const float* ebhh_f = (const float*)d_in[5];
  const float* eWih_b = (const float*)d_in[6];
  const float* eWhh_b = (const float*)d_in[7];
  const float* ebih_b = (const float*)d_in[8];
  const float* ebhh_b = (const float*)d_in[9];
  const float* dWih = (const float*)d_in[10];
  const float* dWhh = (const float*)d_in[11];
  const float* dbih = (const float*)d_in[12];
  const float* dbhh = (const float*)d_in[13];
  const float* WsW  = (const float*)d_in[14];
  const float* Wsb  = (const float*)d_in[15];
  const int* src_tokens  = (const int*)d_in[16];
  const int* src_lengths = (const int*)d_in[17];
  const int* tgt_tokens  = (const int*)d_in[18];
  float* W = (float*)d_ws;

  size_t o = 0;
  auto alloc = [&](size_t n) { size_t r = o; o += (n + 63) & ~(size_t)63; return r; };
  // ---- zeroed region: barrier flags, encoder h ping-pong (buf0 must be 0), rowsum
  const size_t flagsE = alloc(256 * 16);               // int flags, 64B apart
  const size_t flagsD = alloc(256 * 16);
  const size_t ghenc = alloc(32768);                   // 2dir*2buf*32*512 bf16 = 32768 floats
  const size_t rsum  = alloc(BB * TT);
  const size_t zbytes = o * sizeof(float);
  // ---- rest
  const size_t cenc  = alloc(2 * BB * 512);
  const size_t cdec  = alloc(BB * 1024);
  const size_t tlog  = alloc(BB * TT);
  const size_t xg    = alloc((size_t)2 * 1536 * 2048);
  const size_t pre   = alloc((size_t)1536 * 4096);
  const size_t obuf  = alloc((size_t)2 * 1536 * 512 / 2);   // bf16
  const size_t senc  = alloc((size_t)1536 * 1024 / 2);      // bf16
  const size_t gx    = alloc((size_t)2 * 32 * 2048 / 2);    // bf16
  const size_t wdec  = alloc((size_t)4096 * 2048 / 2);      // bf16
  const size_t wenc  = alloc((size_t)2 * 2048 * 512 / 2);   // bf16
  const size_t embbf = alloc(786432 / 2);
  const size_t embRbf= alloc(786432 / 2);
  const size_t dembbf= alloc(786432 / 2);
  const size_t wihfbf= alloc(1048576 / 2);
  const size_t wihbbf= alloc(1048576 / 2);
  const size_t dwihebf = alloc((size_t)4096 * 512 / 2);
  const size_t outsbf  = alloc((size_t)1536 * 2048 / 2);
  const size_t wsbf    = alloc((size_t)VV * 2048 / 2);      // bf16 Ws_W (131 MB)
  const bool wsbf_fit  = (o * sizeof(float)) <= ws_size;

  (void)hipMemsetAsync(W, 0, zbytes, stream);

  embed_src_kernel<<<3072, 256, 0, stream>>>(enc_embed, src_tokens, src_lengths,
                                             (__bf16*)(W + embbf), (__bf16*)(W + embRbf));
  embed_tgt_kernel<<<3072, 256, 0, stream>>>(dec_embed, tgt_tokens, (__bf16*)(W + dembbf));
  f2bf_kernel<<<1024, 256, 0, stream>>>(eWih_f, (__bf16*)(W + wihfbf), 262144);
  f2bf_kernel<<<1024, 256, 0, stream>>>(eWih_b, (__bf16*)(W + wihbbf), 262144);
  f2bf_kernel<<<1024, 256, 0, stream>>>(eWhh_f, (__bf16*)(W + wenc), 262144);
  f2bf_kernel<<<1024, 256, 0, stream>>>(eWhh_b, (__bf16*)(W + wenc) + 1048576, 262144);
  f2bf_slice_kernel<<<8192, 256, 0, stream>>>(dWih, (__bf16*)(W + dwihebf), 4096, 512, 1536, 1024);
  wdec_build_kernel<<<32768, 256, 0, stream>>>(dWih, dWhh, (__bf16*)(W + wdec));
  if (wsbf_fit)
    f2bf_kernel<<<64000, 256, 0, stream>>>(WsW, (__bf16*)(W + wsbf), VV * 2048 / 4);

  gemm_bf16_kernel<<<dim3(12, 16), 256, 0, stream>>>((__bf16*)(W + embbf), (__bf16*)(W + wihfbf),
                                                     ebih_f, ebhh_f, W + xg, 512, 2048);
  gemm_bf16_kernel<<<dim3(12, 16), 256, 0, stream>>>((__bf16*)(W + embRbf), (__bf16*)(W + wihbbf),
                                                     ebih_b, ebhh_b, W + xg + (size_t)1536 * 2048, 512, 2048);
  gemm_bf16_kernel<<<dim3(12, 32), 256, 0, stream>>>((__bf16*)(W + dembbf), (__bf16*)(W + dwihebf),
                                                     dbih, dbhh, W + pre, 512, 4096);

  enc_persistent<<<256, 256, 0, stream>>>((__bf16*)(W + wenc), W + xg, src_lengths,
                                          (__bf16*)(W + ghenc), W + cenc,
                                          (__bf16*)(W + obuf), (int*)(W + flagsE));
  compose_kernel<<<6528, 256, 0, stream>>>((__bf16*)(W + obuf), (__bf16*)(W + ghenc),
                                           W + cenc, src_lengths,
                                           (__bf16*)(W + senc), (__bf16*)(W + gx), W + cdec);
  dec_persistent<<<256, 256, 0, stream>>>((__bf16*)(W + wdec), W + pre, (__bf16*)(W + senc),
                                          src_lengths, W + cdec, (__bf16*)(W + gx),
                                          (__bf16*)(W + outsbf), (int*)(W + flagsD));

  if (wsbf_fit)
    logits_kernel<1><<<dim3(12, 250), 256, 0, stream>>>((const __bf16*)(W + outsbf),
                                                        (const void*)(W + wsbf), Wsb, W + rsum);
  else
    logits_kernel<0><<<dim3(12, 250), 256, 0, stream>>>((const __bf16*)(W + outsbf),
                                                        (const void*)WsW, Wsb, W + rsum);
  tgt_logit_kernel<<<1536, 256, 0, stream>>>((const __bf16*)(W + outsbf), WsW, Wsb, tgt_tokens, W + tlog);
  final_kernel<<<1, 256, 0, stream>>>(W + rsum, W + tlog, tgt_tokens, (float*)d_out);
}

// Round 2
// 1877.375 us; speedup vs baseline: 1.8110x; 1.0706x over previous
//
#include <hip/hip_runtime.h>
#include <hip/hip_bf16.h>
#include <math.h>

#define EE   512
#define HJ   1024
#define VV   32000
#define BB   32
#define SS   48
#define TT   48

typedef float f32x4 __attribute__((ext_vector_type(4)));
typedef __bf16 bf16x8 __attribute__((ext_vector_type(8)));
typedef __bf16 bf16x4 __attribute__((ext_vector_type(4)));

// ---------------------------------------------------------------- coherent access helpers
// Cross-XCD coherence per-access (sc0 sc1 = write-through to / read from MALL).
// Rule used throughout:
//  - cache lines written by MULTIPLE blocks (h-half of x) -> coh read (bypass L2)
//  - cache lines fully written by ONE block (wa-half of x) -> write-through store,
//    PLAIN read: first-touch per-t buffers mean readers' L2/L1 can't hold stale
//    copies, and any writer-side clean allocate is a complete line. Plain reads
//    are L2-shared across the blocks of an XCD (16x traffic reduction).
__device__ __forceinline__ bf16x8 ld_coh_x8(const __bf16* p) {
  bf16x8 r;
  asm volatile("global_load_dwordx4 %0, %1, off sc0 sc1" : "=v"(r) : "v"(p) : "memory");
  return r;
}
__device__ __forceinline__ void st_coh_b16(__bf16* p, __bf16 v) {
  unsigned int w = __builtin_bit_cast(unsigned short, v);
  asm volatile("global_store_short %0, %1, off sc0 sc1" :: "v"(p), "v"(w) : "memory");
}

// ---------------------------------------------------------------- grid barrier
// Decentralized: one flag per block on its own 64B line. All cross-block data is
// written with sc0sc1 (write-through to MALL); the vmcnt(0) drain before the flag
// publish makes it globally visible. NO buffer_wbl2 / buffer_inv anywhere.
// thread i polls block i's flag; nb = number of blocks in the grid.
__device__ __forceinline__ void gbar(int* flags, int step, int nb) {
  asm volatile("s_waitcnt vmcnt(0)" ::: "memory");
  __syncthreads();
  if (threadIdx.x == 0)
    __hip_atomic_store(flags + blockIdx.x * 16, step, __ATOMIC_RELAXED,
                       __HIP_MEMORY_SCOPE_AGENT);
  if (threadIdx.x < nb)
    while (__hip_atomic_load(flags + threadIdx.x * 16, __ATOMIC_RELAXED,
                             __HIP_MEMORY_SCOPE_AGENT) < step)
      __builtin_amdgcn_s_sleep(1);
  __syncthreads();
}

// ---------------------------------------------------------------- embeddings
__global__ void embed_src_kernel(const float* __restrict__ enc_embed,
                                 const int* __restrict__ src_tokens,
                                 const int* __restrict__ src_lengths,
                                 __bf16* __restrict__ emb, __bf16* __restrict__ embR) {
  int idx = blockIdx.x * 256 + threadIdx.x;
  if (idx >= BB * SS * EE) return;
  int e = idx & (EE - 1);
  int bs = idx >> 9;
  int b = bs / SS, s = bs % SS;
  int tok = src_tokens[b * SS + s];
  emb[idx] = (__bf16)enc_embed[(size_t)tok * EE + e];
  int len = src_lengths[b];
  int rs = len - 1 - s; if (rs < 0) rs = 0;
  int tokr = src_tokens[b * SS + rs];
  embR[idx] = (__bf16)enc_embed[(size_t)tokr * EE + e];
}

__global__ void embed_tgt_kernel(const float* __restrict__ dec_embed,
                                 const int* __restrict__ tgt_tokens,
                                 __bf16* __restrict__ demb) {
  int idx = blockIdx.x * 256 + threadIdx.x;
  if (idx >= BB * TT * EE) return;
  int e = idx & (EE - 1);
  int bt = idx >> 9;
  int b = bt / TT, t = bt % TT;
  int tok = tgt_tokens[b * (TT + 1) + t];
  demb[idx] = (__bf16)dec_embed[(size_t)tok * EE + e];
}

// ---------------------------------------------------------------- converts
__global__ void f2bf_kernel(const float* __restrict__ src, __bf16* __restrict__ dst, int n4) {
  int i = blockIdx.x * 256 + threadIdx.x;
  if (i >= n4) return;
  float4 v = ((const float4*)src)[i];
  bf16x4 p = {(__bf16)v.x, (__bf16)v.y, (__bf16)v.z, (__bf16)v.w};
  ((bf16x4*)dst)[i] = p;
}

__global__ void f2bf_slice_kernel(const float* __restrict__ src, __bf16* __restrict__ dst,
                                  int rows, int cols, int ld, int c0) {
  int idx = blockIdx.x * 256 + threadIdx.x;
  if (idx >= rows * cols) return;
  int r = idx / cols, cc = idx % cols;
  dst[idx] = (__bf16)src[(size_t)r * ld + c0 + cc];
}

// Wd[r][k]: k<1024 -> dWih[r][k] (wa cols), else dWhh[r][k-1024]
__global__ void wdec_build_kernel(const float* __restrict__ dWih, const float* __restrict__ dWhh,
                                  __bf16* __restrict__ Wd) {
  int idx = blockIdx.x * 256 + threadIdx.x;
  if (idx >= 4096 * 2048) return;
  int r = idx >> 11, k = idx & 2047;
  float v = (k < 1024) ? dWih[(size_t)r * 1536 + k] : dWhh[(size_t)r * 1024 + (k - 1024)];
  Wd[idx] = (__bf16)v;
}

// senc [32][48][1024] -> sencT [32][1024][48]  (for contiguous wa-phase reads)
__global__ void sencT_build(const __bf16* __restrict__ senc, __bf16* __restrict__ sencT) {
  int b = blockIdx.x >> 4, jt = blockIdx.x & 15;
  int j0c = jt * 64;
  __shared__ __bf16 tile[48][72];
  for (int idx = threadIdx.x; idx < 48 * 64; idx += 256) {
    int s = idx >> 6, j = idx & 63;
    tile[s][j] = senc[((size_t)b * SS + s) * 1024 + j0c + j];
  }
  __syncthreads();
  for (int idx = threadIdx.x; idx < 64 * 48; idx += 256) {
    int j = idx / 48, s = idx - j * 48;
    sencT[((size_t)b * 1024 + j0c + j) * 48 + s] = tile[s][j];
  }
}

// ---------------------------------------------------------------- bf16 MFMA GEMM (NT)
__global__ __launch_bounds__(256) void gemm_bf16_kernel(
    const __bf16* __restrict__ A, const __bf16* __restrict__ Bm,
    const float* __restrict__ bias1, const float* __restrict__ bias2,
    float* __restrict__ C, int K, int N) {
  const int m0 = blockIdx.x * 128;
  const int n0 = blockIdx.y * 128;
  __shared__ __bf16 As[128 * 40];
  __shared__ __bf16 Bs[128 * 40];
  const int tid = threadIdx.x;
  const int lane = tid & 63, wave = tid >> 6;
  const int wm = (wave >> 1) * 64, wn = (wave & 1) * 64;
  const f32x4 zero = {0.f, 0.f, 0.f, 0.f};
  f32x4 acc[4][4];
  for (int i = 0; i < 4; i++) for (int j = 0; j < 4; j++) acc[i][j] = zero;
  const int r = tid >> 2, seg = tid & 3;
  const int mr = lane & 15, q8 = (lane >> 4) * 8;
  for (int k0 = 0; k0 < K; k0 += 32) {
    *(float4*)&As[r * 40 + seg * 8]        = *(const float4*)&A[(size_t)(m0 + r) * K + k0 + seg * 8];
    *(float4*)&As[(r + 64) * 40 + seg * 8] = *(const float4*)&A[(size_t)(m0 + r + 64) * K + k0 + seg * 8];
    *(float4*)&Bs[r * 40 + seg * 8]        = *(const float4*)&Bm[(size_t)(n0 + r) * K + k0 + seg * 8];
    *(float4*)&Bs[(r + 64) * 40 + seg * 8] = *(const float4*)&Bm[(size_t)(n0 + r + 64) * K + k0 + seg * 8];
    __syncthreads();
    bf16x8 af[4], bfr[4];
    for (int i = 0; i < 4; i++) af[i]  = *(const bf16x8*)&As[(wm + i * 16 + mr) * 40 + q8];
    for (int i = 0; i < 4; i++) bfr[i] = *(const bf16x8*)&Bs[(wn + i * 16 + mr) * 40 + q8];
    for (int i = 0; i < 4; i++)
      for (int j = 0; j < 4; j++)
        acc[i][j] = __builtin_amdgcn_mfma_f32_16x16x32_bf16(af[i], bfr[j], acc[i][j], 0, 0, 0);
    __syncthreads();
  }
  const int col = lane & 15, q = lane >> 4;
  for (int i = 0; i < 4; i++) {
    int rowg = m0 + wm + i * 16 + q * 4;
    for (int j = 0; j < 4; j++) {
      int cg = n0 + wn + j * 16 + col;
      float bb = bias1[cg] + bias2[cg];
      for (int rr = 0; rr < 4; rr++)
        C[(size_t)(rowg + rr) * N + cg] = acc[i][j][rr] + bb;
    }
  }
}

// ---------------------------------------------------------------- logits MFMA + exp-sum epilogue
template <int BF>
__global__ __launch_bounds__(256) void logits_kernel(
    const __bf16* __restrict__ A, const void* __restrict__ Braw,
    const float* __restrict__ Wsb, float* __restrict__ rowsum) {
  const int m0 = blockIdx.x * 128;
  const int n0 = blockIdx.y * 128;
  __shared__ __bf16 As[128 * 40];
  __shared__ __bf16 Bs[128 * 40];
  const int tid = threadIdx.x;
  const int lane = tid & 63, wave = tid >> 6;
  const int wm = (wave >> 1) * 64, wn = (wave & 1) * 64;
  const f32x4 zero = {0.f, 0.f, 0.f, 0.f};
  f32x4 acc[4][4];
  for (int i = 0; i < 4; i++) for (int j = 0; j < 4; j++) acc[i][j] = zero;
  const int r = tid >> 2, seg = tid & 3;
  const int rowb = tid >> 1, koff = (tid & 1) * 16;
  const int mr = lane & 15, q8 = (lane >> 4) * 8;
  for (int k0 = 0; k0 < 2048; k0 += 32) {
    *(float4*)&As[r * 40 + seg * 8]        = *(const float4*)&A[(size_t)(m0 + r) * 2048 + k0 + seg * 8];
    *(float4*)&As[(r + 64) * 40 + seg * 8] = *(const float4*)&A[(size_t)(m0 + r + 64) * 2048 + k0 + seg * 8];
    if (BF) {
      const __bf16* Bb = (const __bf16*)Braw;
      *(float4*)&Bs[r * 40 + seg * 8]        = *(const float4*)&Bb[(size_t)(n0 + r) * 2048 + k0 + seg * 8];
      *(float4*)&Bs[(r + 64) * 40 + seg * 8] = *(const float4*)&Bb[(size_t)(n0 + r + 64) * 2048 + k0 + seg * 8];
    } else {
      const float* gb = (const float*)Braw + (size_t)(n0 + rowb) * 2048 + k0 + koff;
      float4 v0 = *(const float4*)(gb);
      float4 v1 = *(const float4*)(gb + 4);
      float4 v2 = *(const float4*)(gb + 8);
      float4 v3 = *(const float4*)(gb + 12);
      bf16x8 p0 = {(__bf16)v0.x,(__bf16)v0.y,(__bf16)v0.z,(__bf16)v0.w,
                   (__bf16)v1.x,(__bf16)v1.y,(__bf16)v1.z,(__bf16)v1.w};
      bf16x8 p1 = {(__bf16)v2.x,(__bf16)v2.y,(__bf16)v2.z,(__bf16)v2.w,
                   (__bf16)v3.x,(__bf16)v3.y,(__bf16)v3.z,(__bf16)v3.w};
      *(bf16x8*)&Bs[rowb * 40 + koff]     = p0;
      *(bf16x8*)&Bs[rowb * 40 + koff + 8] = p1;
    }
    __syncthreads();
    bf16x8 af[4], bfr[4];
    for (int i = 0; i < 4; i++) af[i]  = *(const bf16x8*)&As[(wm + i * 16 + mr) * 40 + q8];
    for (int i = 0; i < 4; i++) bfr[i] = *(const bf16x8*)&Bs[(wn + i * 16 + mr) * 40 + q8];
    for (int i = 0; i < 4; i++)
      for (int j = 0; j < 4; j++)
        acc[i][j] = __builtin_amdgcn_mfma_f32_16x16x32_bf16(af[i], bfr[j], acc[i][j], 0, 0, 0);
    __syncthreads();
  }
  const int col = lane & 15, q = lane >> 4;
  for (int i = 0; i < 4; i++) {
    float s0 = 0, s1 = 0, s2 = 0, s3 = 0;
    for (int j = 0; j < 4; j++) {
      int cg = n0 + wn + j * 16 + col;
      float bb = Wsb[cg];
      s0 += expf(acc[i][j][0] + bb);
      s1 += expf(acc[i][j][1] + bb);
      s2 += expf(acc[i][j][2] + bb);
      s3 += expf(acc[i][j][3] + bb);
    }
    for (int off = 1; off < 16; off <<= 1) {
      s0 += __shfl_xor(s0, off, 64);
      s1 += __shfl_xor(s1, off, 64);
      s2 += __shfl_xor(s2, off, 64);
      s3 += __shfl_xor(s3, off, 64);
    }
    if (col == 0) {
      int rowg = m0 + wm + i * 16 + q * 4;
      atomicAdd(&rowsum[rowg],     s0);
      atomicAdd(&rowsum[rowg + 1], s1);
      atomicAdd(&rowsum[rowg + 2], s2);
      atomicAdd(&rowsum[rowg + 3], s3);
    }
  }
}

// ---------------------------------------------------------------- persistent encoder
__global__ __launch_bounds__(256) void enc_persistent(
    const __bf16* __restrict__ Wenc,   // [2][2048][512] bf16
    const float* __restrict__ xg,      // [2][1536][2048]
    const int* __restrict__ lens,
    __bf16* __restrict__ g_h,          // [2dir][2buf][32*512] bf16 (buf0 zeroed)
    float* __restrict__ cenc,          // [2][32][512]
    __bf16* __restrict__ ob,           // [2][1536][512] masked outputs
    int* __restrict__ flags) {
  const int bk = blockIdx.x;
  const int dir = bk >> 7;
  const int u0 = (bk & 127) * 4;
  const int tid = threadIdx.x;
  const int lane = tid & 63, wave = tid >> 6;
  __shared__ __bf16 Wl[16 * 520];
  __shared__ float gsc[4 * 512];
  __shared__ float cl[128], hloc[128];
  {
    int row = tid >> 4, t16 = tid & 15;
    int g = row >> 2, du = row & 3;
    const __bf16* src = Wenc + ((size_t)dir * 2048 + g * 512 + u0 + du) * 512;
    for (int c = t16 * 32, e = t16 * 32 + 32; c < e; c += 8)
      *(bf16x8*)&Wl[row * 520 + c] = *(const bf16x8*)&src[c];
  }
  if (tid < 128) { cl[tid] = 0.f; hloc[tid] = 0.f; }
  __syncthreads();
  __bf16* ghd = g_h + dir * 32768;
  __bf16* obd = ob + (size_t)dir * (1536 * 512);
  const float* xgd = xg + (size_t)dir * 1536 * 2048;
  const int nr = lane & 15, q8 = (lane >> 4) * 8;
  for (int t = 0; t < SS; t++) {
    const int cur = t & 1;
    const __bf16* hc = ghd + cur * 16384;
    __bf16* hnx = ghd + (cur ^ 1) * 16384;
    float xv[4];
    if (tid < 128) {
      int b = tid >> 2, du = tid & 3;
#pragma unroll
      for (int g = 0; g < 4; g++)
        xv[g] = xgd[((size_t)b * SS + t) * 2048 + g * 512 + u0 + du];
    }
    f32x4 acc0 = {0.f,0.f,0.f,0.f}, acc1 = {0.f,0.f,0.f,0.f};
    const int kb = wave * 128;
    bf16x8 a0[4], a1[4];
#pragma unroll
    for (int ks = 0; ks < 4; ks++) {
      int k0 = kb + ks * 32;
      a0[ks] = ld_coh_x8(&hc[nr * 512 + k0 + q8]);
      a1[ks] = ld_coh_x8(&hc[(nr + 16) * 512 + k0 + q8]);
    }
    asm volatile("s_waitcnt vmcnt(0)" ::: "memory");
    __builtin_amdgcn_sched_barrier(0);
#pragma unroll
    for (int ks = 0; ks < 4; ks++) {
      int k0 = kb + ks * 32;
      bf16x8 bf_ = *(const bf16x8*)&Wl[nr * 520 + k0 + q8];
      acc0 = __builtin_amdgcn_mfma_f32_16x16x32_bf16(a0[ks], bf_, acc0, 0, 0, 0);
      acc1 = __builtin_amdgcn_mfma_f32_16x16x32_bf16(a1[ks], bf_, acc1, 0, 0, 0);
    }
#pragma unroll
    for (int rg = 0; rg < 4; rg++) {
      int m = (lane >> 4) * 4 + rg;
      gsc[wave * 512 + m * 16 + nr]       = acc0[rg];
      gsc[wave * 512 + 256 + m * 16 + nr] = acc1[rg];
    }
    __syncthreads();
    if (tid < 128) {
      int b = tid >> 2, du = tid & 3;
      float gt[4];
#pragma unroll
      for (int g = 0; g < 4; g++) {
        int base = (b >> 4) * 256 + (b & 15) * 16 + g * 4 + du;
        gt[g] = xv[g] + gsc[base] + gsc[512 + base] + gsc[1024 + base] + gsc[1536 + base];
      }
      bool m_ = t < lens[b];
      float cold = cl[tid], hold = hloc[tid];
      float si = 1.f / (1.f + __expf(-gt[0])), sf = 1.f / (1.f + __expf(-gt[1]));
      float so = 1.f / (1.f + __expf(-gt[3]));
      float cn = sf * cold + si * tanhf(gt[2]);
      float hv = so * tanhf(cn);
      float cne = m_ ? cn : cold;
      float hne = m_ ? hv : hold;
      cl[tid] = cne; hloc[tid] = hne;
      st_coh_b16(&hnx[b * 512 + u0 + du], (__bf16)hne);
      obd[((size_t)b * SS + t) * 512 + u0 + du] = m_ ? (__bf16)hv : (__bf16)0.f;
    }
    gbar(flags, t + 1, 256);
  }
  if (tid < 128) {
    int b = tid >> 2, du = tid & 3;
    cenc[(size_t)dir * 16384 + b * 512 + u0 + du] = cl[tid];
  }
}

// ---------------------------------------------------------------- compose
__global__ void compose_kernel(const __bf16* __restrict__ ob, const __bf16* __restrict__ g_h,
                               const float* __restrict__ cenc, const int* __restrict__ lens,
                               __bf16* __restrict__ senc, __bf16* __restrict__ g_x0,
                               float* __restrict__ cdec) {
  int idx = blockIdx.x * 256 + threadIdx.x;
  const int N1 = 1536 * 1024;
  if (idx < N1) {
    int u = idx & 1023, bs = idx >> 10, b = bs / SS, s = bs - b * SS;
    __bf16 v;
    if (u < 512) v = ob[(size_t)bs * 512 + u];
    else {
      int len = lens[b];
      if (s < len) {
        int rs = len - 1 - s;
        v = ob[(size_t)(1536 * 512) + ((size_t)b * SS + rs) * 512 + (u - 512)];
      } else v = (__bf16)0.f;
    }
    senc[idx] = v;
  } else if (idx < N1 + 32 * 2048) {
    int k = idx - N1;
    int b = k >> 11, u = k & 2047;
    __bf16 v = (__bf16)0.f;
    if (u >= 1024) {
      int uu = u - 1024;
      v = (uu < 512) ? g_h[b * 512 + uu] : g_h[32768 + b * 512 + (uu - 512)];
    }
    g_x0[k] = v;
  } else if (idx < N1 + 32 * 2048 + 32 * 1024) {
    int k = idx - N1 - 32 * 2048;
    int b = k >> 10, u = k & 1023;
    cdec[k] = (u < 512) ? cenc[b * 512 + u] : cenc[16384 + b * 512 + (u - 512)];
  }
}

// ---------------------------------------------------------------- persistent decoder
// 128 blocks x 8 u-dims. x buffers are per-timestep (xbuf[t], 49 slots): first-touch
// addresses every step. wa-half (k<1024): single-writer lines -> plain reads (L2-shared).
// h-half (k>=1024): 16B/block interleaved lines -> coherent reads. Wave 0/1 own the
// wa-half k-range, wave 2/3 the h-half, so the load-path split is wave-uniform.
__global__ __launch_bounds__(256) void dec_persistent(
    const __bf16* __restrict__ Wd,     // [4096][2048] bf16
    const float* __restrict__ pre,     // [1536][4096]
    const __bf16* __restrict__ senc,   // [32][48][1024] bf16
    const __bf16* __restrict__ sencT,  // [32][1024][48] bf16
    const int* __restrict__ lens,
    const float* __restrict__ cdec,    // [32][1024]
    __bf16* __restrict__ xbuf,         // [49][32][2048] bf16 (slot0 = wa0|h0)
    __bf16* __restrict__ outs,         // [1536][2048] bf16
    int* __restrict__ flags) {
  const int bk = blockIdx.x;           // 128 blocks
  const int u0 = bk * 8;
  const int tid = threadIdx.x, lane = tid & 63, wave = tid >> 6;
  __shared__ __bf16 Wl[32 * 2056];
  __shared__ float gsc[4 * 1024];
  __shared__ float cl[256];
  __shared__ float asm_l[48];
  {
    // Wl row r = g*8+du  <- Wd row g*1024 + u0 + du
    int row = tid >> 3, t8 = tid & 7;
    int g = row >> 3, du = row & 7;
    const __bf16* src = Wd + (size_t)(g * 1024 + u0 + du) * 2048;
    for (int c = t8 * 256, e = t8 * 256 + 256; c < e; c += 8)
      *(bf16x8*)&Wl[row * 2056 + c] = *(const bf16x8*)&src[c];
  }
  cl[tid] = cdec[(size_t)(tid >> 3) * 1024 + u0 + (tid & 7)];
  __syncthreads();
  const int nr = lane & 15, q8 = (lane >> 4) * 8;
  const int bC = bk >> 2, j0 = (bk & 3) * 256;
  const int b_ = tid >> 3, du_ = tid & 7;
  float xv[4];
#pragma unroll
  for (int g = 0; g < 4; g++)
    xv[g] = pre[((size_t)b_ * TT) * 4096 + g * 1024 + u0 + du_];
  for (int t = 0; t < TT; t++) {
    const __bf16* xc = xbuf + (size_t)t * 65536;
    __bf16* xn = xbuf + (size_t)(t + 1) * 65536;
    f32x4 acc00 = {0.f,0.f,0.f,0.f}, acc01 = {0.f,0.f,0.f,0.f};
    f32x4 acc10 = {0.f,0.f,0.f,0.f}, acc11 = {0.f,0.f,0.f,0.f};
    const int kb = wave * 512;
    bf16x8 a0[16], a1[16];
    if (wave < 2) {                       // k<1024: wa region, single-writer lines
#pragma unroll
      for (int ks = 0; ks < 16; ks++) {
        int k0 = kb + ks * 32;
        a0[ks] = *(const bf16x8*)&xc[nr * 2048 + k0 + q8];
        a1[ks] = *(const bf16x8*)&xc[(nr + 16) * 2048 + k0 + q8];
      }
    } else {                              // k>=1024: h region, multi-writer lines
#pragma unroll
      for (int ks = 0; ks < 16; ks++) {
        int k0 = kb + ks * 32;
        a0[ks] = ld_coh_x8(&xc[nr * 2048 + k0 + q8]);
        a1[ks] = ld_coh_x8(&xc[(nr + 16) * 2048 + k0 + q8]);
      }
      asm volatile("s_waitcnt vmcnt(0)" ::: "memory");
      __builtin_amdgcn_sched_barrier(0);
    }
#pragma unroll
    for (int ks = 0; ks < 16; ks++) {
      int k0 = kb + ks * 32;
      bf16x8 b0 = *(const bf16x8*)&Wl[nr * 2056 + k0 + q8];
      bf16x8 b1 = *(const bf16x8*)&Wl[(nr + 16) * 2056 + k0 + q8];
      acc00 = __builtin_amdgcn_mfma_f32_16x16x32_bf16(a0[ks], b0, acc00, 0, 0, 0);
      acc01 = __builtin_amdgcn_mfma_f32_16x16x32_bf16(a0[ks], b1, acc01, 0, 0, 0);
      acc10 = __builtin_amdgcn_mfma_f32_16x16x32_bf16(a1[ks], b0, acc10, 0, 0, 0);
      acc11 = __builtin_amdgcn_mfma_f32_16x16x32_bf16(a1[ks], b1, acc11, 0, 0, 0);
    }
#pragma unroll
    for (int rg = 0; rg < 4; rg++) {
      int m = (lane >> 4) * 4 + rg;
      gsc[wave * 1024 + m * 32 + nr]             = acc00[rg];
      gsc[wave * 1024 + m * 32 + 16 + nr]        = acc01[rg];
      gsc[wave * 1024 + (16 + m) * 32 + nr]      = acc10[rg];
      gsc[wave * 1024 + (16 + m) * 32 + 16 + nr] = acc11[rg];
    }
    __syncthreads();
    {
      float gt[4];
#pragma unroll
      for (int g = 0; g < 4; g++) {
        int base = b_ * 32 + g * 8 + du_;
        gt[g] = xv[g] + gsc[base] + gsc[1024 + base] + gsc[2048 + base] + gsc[3072 + base];
      }
      float cold = cl[tid];
      float si = 1.f / (1.f + __expf(-gt[0])), sf = 1.f / (1.f + __expf(-gt[1]));
      float so = 1.f / (1.f + __expf(-gt[3]));
      float cn = sf * cold + si * tanhf(gt[2]);
      float hv = so * tanhf(cn);
      cl[tid] = cn;
      __bf16 hb = (__bf16)hv;
      st_coh_b16(&xn[b_ * 2048 + 1024 + u0 + du_], hb);          // cross-block
      outs[((size_t)b_ * TT + t) * 2048 + 1024 + u0 + du_] = hb; // post-kernel
    }
    if (t + 1 < TT) {   // prefetch next pre-slice; latency hides under the barrier
#pragma unroll
      for (int g = 0; g < 4; g++)
        xv[g] = pre[((size_t)b_ * TT + t + 1) * 4096 + g * 1024 + u0 + du_];
    }
    gbar(flags, 2 * t + 1, 128);       // h(t) visible everywhere
    // ---- attention: each block computes align+softmax for its bC (4x redundant)
    {
      int len = lens[bC];
      const __bf16* hh = xn + bC * 2048 + 1024;
      bf16x8 h0 = ld_coh_x8(&hh[lane * 16]);     // multi-writer lines -> coherent
      bf16x8 h1 = ld_coh_x8(&hh[lane * 16 + 8]);
      asm volatile("s_waitcnt vmcnt(0)" ::: "memory");
      __builtin_amdgcn_sched_barrier(0);
      float hf[16];
#pragma unroll
      for (int i = 0; i < 8; i++) { hf[i] = (float)h0[i]; hf[8 + i] = (float)h1[i]; }
      for (int si = 0; si < 12; si++) {
        int s = wave * 12 + si;
        if (s >= len) { if (lane == 0) asm_l[s] = -1e30f; continue; }
        const __bf16* se = senc + ((size_t)bC * SS + s) * 1024;   // read-only, L2-hot
        bf16x8 s0 = *(const bf16x8*)&se[lane * 16];
        bf16x8 s1 = *(const bf16x8*)&se[lane * 16 + 8];
        float p = 0.f;
#pragma unroll
        for (int i = 0; i < 8; i++) p += (float)s0[i] * hf[i] + (float)s1[i] * hf[8 + i];
#pragma unroll
        for (int off = 32; off > 0; off >>= 1) p += __shfl_xor(p, off, 64);
        if (lane == 0) asm_l[s] = p;
      }
      __syncthreads();
      if (wave == 0) {
        float a = (lane < SS) ? asm_l[lane] : -1e30f;
        float mx = a;
#pragma unroll
        for (int off = 32; off > 0; off >>= 1) mx = fmaxf(mx, __shfl_xor(mx, off, 64));
        float p = (lane < SS) ? __expf(a - mx) : 0.f;
        float sm = p;
#pragma unroll
        for (int off = 32; off > 0; off >>= 1) sm += __shfl_xor(sm, off, 64);
        if (lane < SS) asm_l[lane] = p / sm;
      }
      __syncthreads();
      {
        int j = j0 + tid;
        const __bf16* srow = sencT + ((size_t)bC * 1024 + j) * 48;  // contiguous 48
        bf16x8 v0 = *(const bf16x8*)&srow[0];
        bf16x8 v1 = *(const bf16x8*)&srow[8];
        bf16x8 v2 = *(const bf16x8*)&srow[16];
        bf16x8 v3 = *(const bf16x8*)&srow[24];
        bf16x8 v4 = *(const bf16x8*)&srow[32];
        bf16x8 v5 = *(const bf16x8*)&srow[40];
        float w = 0.f;
#pragma unroll
        for (int i = 0; i < 8; i++) {
          w += asm_l[i]      * (float)v0[i];
          w += asm_l[8 + i]  * (float)v1[i];
          w += asm_l[16 + i] * (float)v2[i];
          w += asm_l[24 + i] * (float)v3[i];
          w += asm_l[32 + i] * (float)v4[i];
          w += asm_l[40 + i] * (float)v5[i];
        }
        __bf16 wb = (__bf16)w;
        st_coh_b16(&xn[bC * 2048 + j], wb);             // single-writer lines (512B/block)
        outs[((size_t)bC * TT + t) * 2048 + j] = wb;    // post-kernel
      }
    }
    gbar(flags, 2 * t + 2, 128);       // wa(t) visible everywhere
  }
}

// ---------------------------------------------------------------- target logit per row
__global__ __launch_bounds__(256) void tgt_logit_kernel(
    const __bf16* __restrict__ outs_bf, const float* __restrict__ WsW,
    const float* __restrict__ Wsb, const int* __restrict__ tgt_tokens,
    float* __restrict__ tlogit) {
  const int r = blockIdx.x;
  const int b = r / TT, t = r % TT;
  const int tgt = tgt_tokens[b * (TT + 1) + t + 1];
  const __bf16* a = outs_bf + (size_t)r * 2048;
  const float* w = WsW + (size_t)tgt * 2048;
  const int tid = threadIdx.x;
  float p = 0;
  for (int k = tid; k < 2048; k += 256) p += (float)a[k] * w[k];
  for (int off = 32; off > 0; off >>= 1) p += __shfl_down(p, off, 64);
  __shared__ float red[4];
  if ((tid & 63) == 0) red[tid >> 6] = p;
  __syncthreads();
  if (tid == 0) tlogit[r] = red[0] + red[1] + red[2] + red[3] + Wsb[tgt];
}

// ---------------------------------------------------------------- final reduce
__global__ void final_kernel(const float* __restrict__ rowsum, const float* __restrict__ tlogit,
                             const int* __restrict__ tgt_tokens, float* __restrict__ out) {
  const int tid = threadIdx.x;
  float s = 0;
  for (int r = tid; r < BB * TT; r += 256) {
    int b = r / TT, t = r % TT;
    int tgt = tgt_tokens[b * (TT + 1) + t + 1];
    if (tgt != 0) s += logf(rowsum[r]) - tlogit[r];
  }
  for (int off = 32; off > 0; off >>= 1) s += __shfl_down(s, off, 64);
  __shared__ float red[4];
  if ((tid & 63) == 0) red[tid >> 6] = s;
  __syncthreads();
  if (tid == 0) out[0] = red[0] + red[1] + red[2] + red[3];
}

// ================================================================ host
extern "C" void kernel_launch(void* const* d_in, const int* in_sizes, int n_in,
                              void* d_out, int out_size, void* d_ws, size_t ws_size,
                              hipStream_t stream) {
  const float* enc_embed = (const float*)d_in[0];
  const float* dec_embed = (const float*)d_in[1];
  const float* eWih_f = (const float*)d_in[2];
  const float* eWhh_f = (const float*)d_in[3];
  const float* ebih_f = (const float*)d_in[4];
  const float* ebhh_f = (const float*)d_in[5];
  const float* eWih_b = (const float*)d_in[6];
  const float* eWhh_b = (const float*)d_in[7];
  const float* ebih_b = (const float*)d_in[8];
  const float* ebhh_b = (const float*)d_in[9];
  const float* dWih = (const float*)d_in[10];
  const float* dWhh = (const float*)d_in[11];
  const float* dbih = (const float*)d_in[12];
  const float* dbhh = (const float*)d_in[13];
  const float* WsW  = (const float*)d_in[14];
  const float* Wsb  = (const float*)d_in[15];
  const int* src_tokens  = (const int*)d_in[16];
  const int* src_lengths = (const int*)d_in[17];
  const int* tgt_tokens  = (const int*)d_in[18];
  float* W = (float*)d_ws;

  size_t o = 0;
  auto alloc = [&](size_t n) { size_t r = o; o += (n + 63) & ~(size_t)63; return r; };
  // ---- zeroed region: barrier flags, encoder h ping-pong (buf0 must be 0), rowsum
  const size_t flagsE = alloc(256 * 16);               // int flags, 64B apart
  const size_t flagsD = alloc(256 * 16);
  const size_t ghenc = alloc(32768);                   // 2dir*2buf*32*512 bf16
  const size_t rsum  = alloc(BB * TT);
  const size_t zbytes = o * sizeof(float);
  // ---- rest
  const size_t cenc  = alloc(2 * BB * 512);
  const size_t cdec  = alloc(BB * 1024);
  const size_t tlog  = alloc(BB * TT);
  const size_t xg    = alloc((size_t)2 * 1536 * 2048);
  const size_t pre   = alloc((size_t)1536 * 4096);
  const size_t obuf  = alloc((size_t)2 * 1536 * 512 / 2);   // bf16
  const size_t senc  = alloc((size_t)1536 * 1024 / 2);      // bf16
  const size_t sencT = alloc((size_t)32 * 1024 * 48 / 2);   // bf16 transposed
  const size_t gx    = alloc((size_t)49 * 32 * 2048 / 2);   // bf16, 49 per-t slots
  const size_t wdec  = alloc((size_t)4096 * 2048 / 2);      // bf16
  const size_t wenc  = alloc((size_t)2 * 2048 * 512 / 2);   // bf16
  const size_t embbf = alloc(786432 / 2);
  const size_t embRbf= alloc(786432 / 2);
  const size_t dembbf= alloc(786432 / 2);
  const size_t wihfbf= alloc(1048576 / 2);
  const size_t wihbbf= alloc(1048576 / 2);
  const size_t dwihebf = alloc((size_t)4096 * 512 / 2);
  const size_t outsbf  = alloc((size_t)1536 * 2048 / 2);
  const size_t wsbf    = alloc((size_t)VV * 2048 / 2);      // bf16 Ws_W (131 MB)
  const bool wsbf_fit  = (o * sizeof(float)) <= ws_size;

  (void)hipMemsetAsync(W, 0, zbytes, stream);

  embed_src_kernel<<<3072, 256, 0, stream>>>(enc_embed, src_tokens, src_lengths,
                                             (__bf16*)(W + embbf), (__bf16*)(W + embRbf));
  embed_tgt_kernel<<<3072, 256, 0, stream>>>(dec_embed, tgt_tokens, (__bf16*)(W + dembbf));
  f2bf_kernel<<<1024, 256, 0, stream>>>(eWih_f, (__bf16*)(W + wihfbf), 262144);
  f2bf_kernel<<<1024, 256, 0, stream>>>(eWih_b, (__bf16*)(W + wihbbf), 262144);
  f2bf_kernel<<<1024, 256, 0, stream>>>(eWhh_f, (__bf16*)(W + wenc), 262144);
  f2bf_kernel<<<1024, 256, 0, stream>>>(eWhh_b, (__bf16*)(W + wenc) + 1048576, 262144);
  f2bf_slice_kernel<<<8192, 256, 0, stream>>>(dWih, (__bf16*)(W + dwihebf), 4096, 512, 1536, 1024);
  wdec_build_kernel<<<32768, 256, 0, stream>>>(dWih, dWhh, (__bf16*)(W + wdec));
  if (wsbf_fit)
    f2bf_kernel<<<64000, 256, 0, stream>>>(WsW, (__bf16*)(W + wsbf), VV * 2048 / 4);

  gemm_bf16_kernel<<<dim3(12, 16), 256, 0, stream>>>((__bf16*)(W + embbf), (__bf16*)(W + wihfbf),
                                                     ebih_f, ebhh_f, W + xg, 512, 2048);
  gemm_bf16_kernel<<<dim3(12, 16), 256, 0, stream>>>((__bf16*)(W + embRbf), (__bf16*)(W + wihbbf),
                                                     ebih_b, ebhh_b, W + xg + (size_t)1536 * 2048, 512, 2048);
  gemm_bf16_kernel<<<dim3(12, 32), 256, 0, stream>>>((__bf16*)(W + dembbf), (__bf16*)(W + dwihebf),
                                                     dbih, dbhh, W + pre, 512, 4096);

  enc_persistent<<<256, 256, 0, stream>>>((__bf16*)(W + wenc), W + xg, src_lengths,
                                          (__bf16*)(W + ghenc), W + cenc,
                                          (__bf16*)(W + obuf), (int*)(W + flagsE));
  compose_kernel<<<6528, 256, 0, stream>>>((__bf16*)(W + obuf), (__bf16*)(W + ghenc),
                                           W + cenc, src_lengths,
                                           (__bf16*)(W + senc), (__bf16*)(W + gx), W + cdec);
  sencT_build<<<512, 256, 0, stream>>>((const __bf16*)(W + senc), (__bf16*)(W + sencT));
  dec_persistent<<<128, 256, 0, stream>>>((__bf16*)(W + wdec), W + pre, (__bf16*)(W + senc),
                                          (const __bf16*)(W + sencT),
                                          src_lengths, W + cdec, (__bf16*)(W + gx),
                                          (__bf16*)(W + outsbf), (int*)(W + flagsD));

  if (wsbf_fit)
    logits_kernel<1><<<dim3(12, 250), 256, 0, stream>>>((const __bf16*)(W + outsbf),
                                                        (const void*)(W + wsbf), Wsb, W + rsum);
  else
    logits_kernel<0><<<dim3(12, 250), 256, 0, stream>>>((const __bf16*)(W + outsbf),
                                                        (const void*)WsW, Wsb, W + rsum);
  tgt_logit_kernel<<<1536, 256, 0, stream>>>((const __bf16*)(W + outsbf), WsW, Wsb, tgt_tokens, W + tlog);
  final_kernel<<<1, 256, 0, stream>>>(W + rsum, W + tlog, tgt_tokens, (float*)d_out);
}

// Round 4
// 1598.157 us; speedup vs baseline: 2.1275x; 1.1747x over previous
//
#include <hip/hip_runtime.h>
#include <hip/hip_bf16.h>
#include <math.h>

#define EE   512
#define HJ   1024
#define VV   32000
#define BB   32
#define SS   48
#define TT   48

typedef float f32x4 __attribute__((ext_vector_type(4)));
typedef __bf16 bf16x8 __attribute__((ext_vector_type(8)));
typedef __bf16 bf16x4 __attribute__((ext_vector_type(4)));

// ---------------------------------------------------------------- coherent access helpers
// Cross-XCD coherence per-access (sc0 sc1 = write-through to / read from MALL).
//  - multi-writer cache lines (h-half of x) -> coh read (bypass L2)
//  - single-writer fully-written lines (wa-half) -> write-through store, plain read
__device__ __forceinline__ bf16x8 ld_coh_x8(const __bf16* p) {
  bf16x8 r;
  asm volatile("global_load_dwordx4 %0, %1, off sc0 sc1" : "=v"(r) : "v"(p) : "memory");
  return r;
}
__device__ __forceinline__ void st_coh_b16(__bf16* p, __bf16 v) {
  unsigned int w = __builtin_bit_cast(unsigned short, v);
  asm volatile("global_store_short %0, %1, off sc0 sc1" :: "v"(p), "v"(w) : "memory");
}

// global -> LDS direct staging, 16B per lane (lane l writes ldsbase + l*16).
// m97-verified template: wave-uniform LDS base, linear destination.
__device__ __forceinline__ void glds16(const __bf16* g, __bf16* l) {
  __builtin_amdgcn_global_load_lds(
      (const __attribute__((address_space(1))) unsigned int*)g,
      (__attribute__((address_space(3))) unsigned int*)l, 16, 0, 0);
}

// ---------------------------------------------------------------- grid barrier
// Decentralized flags, one 64B line per block-slot. vmcnt(0) drain before publish
// makes all sc0sc1 data globally visible. No buffer_wbl2 / buffer_inv anywhere.
__device__ __forceinline__ void gbar(int* flags, int step, int nb, int slot) {
  asm volatile("s_waitcnt vmcnt(0)" ::: "memory");
  __syncthreads();
  if (threadIdx.x == 0)
    __hip_atomic_store(flags + slot * 16, step, __ATOMIC_RELAXED,
                       __HIP_MEMORY_SCOPE_AGENT);
  if ((int)threadIdx.x < nb)
    while (__hip_atomic_load(flags + threadIdx.x * 16, __ATOMIC_RELAXED,
                             __HIP_MEMORY_SCOPE_AGENT) < step)
      __builtin_amdgcn_s_sleep(1);
  __syncthreads();
}

// ---------------------------------------------------------------- embeddings
__global__ void embed_src_kernel(const float* __restrict__ enc_embed,
                                 const int* __restrict__ src_tokens,
                                 const int* __restrict__ src_lengths,
                                 __bf16* __restrict__ emb, __bf16* __restrict__ embR) {
  int idx = blockIdx.x * 256 + threadIdx.x;
  if (idx >= BB * SS * EE) return;
  int e = idx & (EE - 1);
  int bs = idx >> 9;
  int b = bs / SS, s = bs % SS;
  int tok = src_tokens[b * SS + s];
  emb[idx] = (__bf16)enc_embed[(size_t)tok * EE + e];
  int len = src_lengths[b];
  int rs = len - 1 - s; if (rs < 0) rs = 0;
  int tokr = src_tokens[b * SS + rs];
  embR[idx] = (__bf16)enc_embed[(size_t)tokr * EE + e];
}

__global__ void embed_tgt_kernel(const float* __restrict__ dec_embed,
                                 const int* __restrict__ tgt_tokens,
                                 __bf16* __restrict__ demb) {
  int idx = blockIdx.x * 256 + threadIdx.x;
  if (idx >= BB * TT * EE) return;
  int e = idx & (EE - 1);
  int bt = idx >> 9;
  int b = bt / TT, t = bt % TT;
  int tok = tgt_tokens[b * (TT + 1) + t];
  demb[idx] = (__bf16)dec_embed[(size_t)tok * EE + e];
}

// ---------------------------------------------------------------- converts
__global__ void f2bf_kernel(const float* __restrict__ src, __bf16* __restrict__ dst, int n4) {
  int i = blockIdx.x * 256 + threadIdx.x;
  if (i >= n4) return;
  float4 v = ((const float4*)src)[i];
  bf16x4 p = {(__bf16)v.x, (__bf16)v.y, (__bf16)v.z, (__bf16)v.w};
  ((bf16x4*)dst)[i] = p;
}

__global__ void f2bf_slice_kernel(const float* __restrict__ src, __bf16* __restrict__ dst,
                                  int rows, int cols, int ld, int c0) {
  int idx = blockIdx.x * 256 + threadIdx.x;
  if (idx >= rows * cols) return;
  int r = idx / cols, cc = idx % cols;
  dst[idx] = (__bf16)src[(size_t)r * ld + c0 + cc];
}

// Wd[r][k]: k<1024 -> dWih[r][k] (wa cols), else dWhh[r][k-1024]
__global__ void wdec_build_kernel(const float* __restrict__ dWih, const float* __restrict__ dWhh,
                                  __bf16* __restrict__ Wd) {
  int idx = blockIdx.x * 256 + threadIdx.x;
  if (idx >= 4096 * 2048) return;
  int r = idx >> 11, k = idx & 2047;
  float v = (k < 1024) ? dWih[(size_t)r * 1536 + k] : dWhh[(size_t)r * 1024 + (k - 1024)];
  Wd[idx] = (__bf16)v;
}

// senc [32][48][1024] -> sencT [32][1024][48]
__global__ void sencT_build(const __bf16* __restrict__ senc, __bf16* __restrict__ sencT) {
  int b = blockIdx.x >> 4, jt = blockIdx.x & 15;
  int j0c = jt * 64;
  __shared__ __bf16 tile[48][72];
  for (int idx = threadIdx.x; idx < 48 * 64; idx += 256) {
    int s = idx >> 6, j = idx & 63;
    tile[s][j] = senc[((size_t)b * SS + s) * 1024 + j0c + j];
  }
  __syncthreads();
  for (int idx = threadIdx.x; idx < 64 * 48; idx += 256) {
    int j = idx / 48, s = idx - j * 48;
    sencT[((size_t)b * 1024 + j0c + j) * 48 + s] = tile[s][j];
  }
}

// ---------------------------------------------------------------- bf16 MFMA GEMM (NT)
__global__ __launch_bounds__(256) void gemm_bf16_kernel(
    const __bf16* __restrict__ A, const __bf16* __restrict__ Bm,
    const float* __restrict__ bias1, const float* __restrict__ bias2,
    float* __restrict__ C, int K, int N) {
  const int m0 = blockIdx.x * 128;
  const int n0 = blockIdx.y * 128;
  __shared__ __bf16 As[128 * 40];
  __shared__ __bf16 Bs[128 * 40];
  const int tid = threadIdx.x;
  const int lane = tid & 63, wave = tid >> 6;
  const int wm = (wave >> 1) * 64, wn = (wave & 1) * 64;
  const f32x4 zero = {0.f, 0.f, 0.f, 0.f};
  f32x4 acc[4][4];
  for (int i = 0; i < 4; i++) for (int j = 0; j < 4; j++) acc[i][j] = zero;
  const int r = tid >> 2, seg = tid & 3;
  const int mr = lane & 15, q8 = (lane >> 4) * 8;
  for (int k0 = 0; k0 < K; k0 += 32) {
    *(float4*)&As[r * 40 + seg * 8]        = *(const float4*)&A[(size_t)(m0 + r) * K + k0 + seg * 8];
    *(float4*)&As[(r + 64) * 40 + seg * 8] = *(const float4*)&A[(size_t)(m0 + r + 64) * K + k0 + seg * 8];
    *(float4*)&Bs[r * 40 + seg * 8]        = *(const float4*)&Bm[(size_t)(n0 + r) * K + k0 + seg * 8];
    *(float4*)&Bs[(r + 64) * 40 + seg * 8] = *(const float4*)&Bm[(size_t)(n0 + r + 64) * K + k0 + seg * 8];
    __syncthreads();
    bf16x8 af[4], bfr[4];
    for (int i = 0; i < 4; i++) af[i]  = *(const bf16x8*)&As[(wm + i * 16 + mr) * 40 + q8];
    for (int i = 0; i < 4; i++) bfr[i] = *(const bf16x8*)&Bs[(wn + i * 16 + mr) * 40 + q8];
    for (int i = 0; i < 4; i++)
      for (int j = 0; j < 4; j++)
        acc[i][j] = __builtin_amdgcn_mfma_f32_16x16x32_bf16(af[i], bfr[j], acc[i][j], 0, 0, 0);
    __syncthreads();
  }
  const int col = lane & 15, q = lane >> 4;
  for (int i = 0; i < 4; i++) {
    int rowg = m0 + wm + i * 16 + q * 4;
    for (int j = 0; j < 4; j++) {
      int cg = n0 + wn + j * 16 + col;
      float bb = bias1[cg] + bias2[cg];
      for (int rr = 0; rr < 4; rr++)
        C[(size_t)(rowg + rr) * N + cg] = acc[i][j][rr] + bb;
    }
  }
}

// ---------------------------------------------------------------- logits MFMA + exp-sum epilogue
// BF=1: B pre-converted bf16; staging via global_load_lds into linear [128][32] LDS
// (m97 structure). Wave w stages rows [w*32, w*32+32) of both tiles:
// lane l covers (row w*32 + (l>>2) [+16 for 2nd call], col (l&3)*8).
// BF=0: fp32 fallback (reg-staged, stride-40 LDS).
template <int BF>
__global__ __launch_bounds__(256) void logits_kernel(
    const __bf16* __restrict__ A, const void* __restrict__ Braw,
    const float* __restrict__ Wsb, float* __restrict__ rowsum) {
  const int m0 = blockIdx.x * 128;
  const int n0 = blockIdx.y * 128;
  __shared__ __bf16 As[128 * 40];
  __shared__ __bf16 Bs[128 * 40];
  const int tid = threadIdx.x;
  const int lane = tid & 63, wave = tid >> 6;
  const int wm = (wave >> 1) * 64, wn = (wave & 1) * 64;
  const f32x4 zero = {0.f, 0.f, 0.f, 0.f};
  f32x4 acc[4][4];
  for (int i = 0; i < 4; i++) for (int j = 0; j < 4; j++) acc[i][j] = zero;
  const int mr = lane & 15, q8 = (lane >> 4) * 8;
  if (BF) {
    const __bf16* Bb = (const __bf16*)Braw;
    const int srow = lane >> 2, scol = (lane & 3) * 8;
    const int wrow = wave * 32;
    const __bf16* gA0 = A  + (size_t)(m0 + wrow + srow) * 2048 + scol;
    const __bf16* gA1 = A  + (size_t)(m0 + wrow + 16 + srow) * 2048 + scol;
    const __bf16* gB0 = Bb + (size_t)(n0 + wrow + srow) * 2048 + scol;
    const __bf16* gB1 = Bb + (size_t)(n0 + wrow + 16 + srow) * 2048 + scol;
    __bf16* lA0 = &As[wrow * 32];
    __bf16* lA1 = &As[(wrow + 16) * 32];
    __bf16* lB0 = &Bs[wrow * 32];
    __bf16* lB1 = &Bs[(wrow + 16) * 32];
    for (int k0 = 0; k0 < 2048; k0 += 32) {
      glds16(gA0 + k0, lA0);
      glds16(gA1 + k0, lA1);
      glds16(gB0 + k0, lB0);
      glds16(gB1 + k0, lB1);
      __syncthreads();   // compiler emits vmcnt(0) drain before s_barrier
      bf16x8 af[4], bfr[4];
      for (int i = 0; i < 4; i++) af[i]  = *(const bf16x8*)&As[(wm + i * 16 + mr) * 32 + q8];
      for (int i = 0; i < 4; i++) bfr[i] = *(const bf16x8*)&Bs[(wn + i * 16 + mr) * 32 + q8];
      for (int i = 0; i < 4; i++)
        for (int j = 0; j < 4; j++)
          acc[i][j] = __builtin_amdgcn_mfma_f32_16x16x32_bf16(af[i], bfr[j], acc[i][j], 0, 0, 0);
      __syncthreads();
    }
  } else {
    const int rowb = tid >> 1, koff = (tid & 1) * 16;
    const int r = tid >> 2, seg = tid & 3;
    for (int k0 = 0; k0 < 2048; k0 += 32) {
      *(float4*)&As[r * 40 + seg * 8]        = *(const float4*)&A[(size_t)(m0 + r) * 2048 + k0 + seg * 8];
      *(float4*)&As[(r + 64) * 40 + seg * 8] = *(const float4*)&A[(size_t)(m0 + r + 64) * 2048 + k0 + seg * 8];
      const float* gb = (const float*)Braw + (size_t)(n0 + rowb) * 2048 + k0 + koff;
      float4 v0 = *(const float4*)(gb);
      float4 v1 = *(const float4*)(gb + 4);
      float4 v2 = *(const float4*)(gb + 8);
      float4 v3 = *(const float4*)(gb + 12);
      bf16x8 p0 = {(__bf16)v0.x,(__bf16)v0.y,(__bf16)v0.z,(__bf16)v0.w,
                   (__bf16)v1.x,(__bf16)v1.y,(__bf16)v1.z,(__bf16)v1.w};
      bf16x8 p1 = {(__bf16)v2.x,(__bf16)v2.y,(__bf16)v2.z,(__bf16)v2.w,
                   (__bf16)v3.x,(__bf16)v3.y,(__bf16)v3.z,(__bf16)v3.w};
      *(bf16x8*)&Bs[rowb * 40 + koff]     = p0;
      *(bf16x8*)&Bs[rowb * 40 + koff + 8] = p1;
      __syncthreads();
      bf16x8 af[4], bfr[4];
      for (int i = 0; i < 4; i++) af[i]  = *(const bf16x8*)&As[(wm + i * 16 + mr) * 40 + q8];
      for (int i = 0; i < 4; i++) bfr[i] = *(const bf16x8*)&Bs[(wn + i * 16 + mr) * 40 + q8];
      for (int i = 0; i < 4; i++)
        for (int j = 0; j < 4; j++)
          acc[i][j] = __builtin_amdgcn_mfma_f32_16x16x32_bf16(af[i], bfr[j], acc[i][j], 0, 0, 0);
      __syncthreads();
    }
  }
  const int col = lane & 15, q = lane >> 4;
  for (int i = 0; i < 4; i++) {
    float s0 = 0, s1 = 0, s2 = 0, s3 = 0;
    for (int j = 0; j < 4; j++) {
      int cg = n0 + wn + j * 16 + col;
      float bb = Wsb[cg];
      s0 += expf(acc[i][j][0] + bb);
      s1 += expf(acc[i][j][1] + bb);
      s2 += expf(acc[i][j][2] + bb);
      s3 += expf(acc[i][j][3] + bb);
    }
    for (int off = 1; off < 16; off <<= 1) {
      s0 += __shfl_xor(s0, off, 64);
      s1 += __shfl_xor(s1, off, 64);
      s2 += __shfl_xor(s2, off, 64);
      s3 += __shfl_xor(s3, off, 64);
    }
    if (col == 0) {
      int rowg = m0 + wm + i * 16 + q * 4;
      atomicAdd(&rowsum[rowg],     s0);
      atomicAdd(&rowsum[rowg + 1], s1);
      atomicAdd(&rowsum[rowg + 2], s2);
      atomicAdd(&rowsum[rowg + 3], s3);
    }
  }
}

// ---------------------------------------------------------------- persistent encoder
__global__ __launch_bounds__(256) void enc_persistent(
    const __bf16* __restrict__ Wenc,   // [2][2048][512] bf16
    const float* __restrict__ xg,      // [2][1536][2048]
    const int* __restrict__ lens,
    __bf16* __restrict__ g_h,          // [2dir][2buf][32*512] bf16 (buf0 zeroed)
    float* __restrict__ cenc,          // [2][32][512]
    __bf16* __restrict__ ob,           // [2][1536][512] masked outputs
    int* __restrict__ flags) {
  const int bk = blockIdx.x;
  const int dir = bk >> 7;
  const int u0 = (bk & 127) * 4;
  const int tid = threadIdx.x;
  const int lane = tid & 63, wave = tid >> 6;
  __shared__ __bf16 Wl[16 * 520];
  __shared__ float gsc[4 * 512];
  __shared__ float cl[128], hloc[128];
  {
    int row = tid >> 4, t16 = tid & 15;
    int g = row >> 2, du = row & 3;
    const __bf16* src = Wenc + ((size_t)dir * 2048 + g * 512 + u0 + du) * 512;
    for (int c = t16 * 32, e = t16 * 32 + 32; c < e; c += 8)
      *(bf16x8*)&Wl[row * 520 + c] = *(const bf16x8*)&src[c];
  }
  if (tid < 128) { cl[tid] = 0.f; hloc[tid] = 0.f; }
  __syncthreads();
  __bf16* ghd = g_h + dir * 32768;
  __bf16* obd = ob + (size_t)dir * (1536 * 512);
  const float* xgd = xg + (size_t)dir * 1536 * 2048;
  const int nr = lane & 15, q8 = (lane >> 4) * 8;
  // hoist len + prefetch first xv slice (loads drain at the barrier)
  int lb = 0;
  float xv[4];
  if (tid < 128) {
    int b = tid >> 2, du = tid & 3;
    lb = lens[b];
#pragma unroll
    for (int g = 0; g < 4; g++)
      xv[g] = xgd[((size_t)b * SS) * 2048 + g * 512 + u0 + du];
  }
  for (int t = 0; t < SS; t++) {
    const int cur = t & 1;
    const __bf16* hc = ghd + cur * 16384;
    __bf16* hnx = ghd + (cur ^ 1) * 16384;
    f32x4 acc0 = {0.f,0.f,0.f,0.f}, acc1 = {0.f,0.f,0.f,0.f};
    const int kb = wave * 128;
    bf16x8 a0[4], a1[4];
#pragma unroll
    for (int ks = 0; ks < 4; ks++) {
      int k0 = kb + ks * 32;
      a0[ks] = ld_coh_x8(&hc[nr * 512 + k0 + q8]);
      a1[ks] = ld_coh_x8(&hc[(nr + 16) * 512 + k0 + q8]);
    }
    asm volatile("s_waitcnt vmcnt(0)" ::: "memory");
    __builtin_amdgcn_sched_barrier(0);
#pragma unroll
    for (int ks = 0; ks < 4; ks++) {
      int k0 = kb + ks * 32;
      bf16x8 bf_ = *(const bf16x8*)&Wl[nr * 520 + k0 + q8];
      acc0 = __builtin_amdgcn_mfma_f32_16x16x32_bf16(a0[ks], bf_, acc0, 0, 0, 0);
      acc1 = __builtin_amdgcn_mfma_f32_16x16x32_bf16(a1[ks], bf_, acc1, 0, 0, 0);
    }
#pragma unroll
    for (int rg = 0; rg < 4; rg++) {
      int m = (lane >> 4) * 4 + rg;
      gsc[wave * 512 + m * 16 + nr]       = acc0[rg];
      gsc[wave * 512 + 256 + m * 16 + nr] = acc1[rg];
    }
    __syncthreads();
    if (tid < 128) {
      int b = tid >> 2, du = tid & 3;
      float gt[4];
#pragma unroll
      for (int g = 0; g < 4; g++) {
        int base = (b >> 4) * 256 + (b & 15) * 16 + g * 4 + du;
        gt[g] = xv[g] + gsc[base] + gsc[512 + base] + gsc[1024 + base] + gsc[1536 + base];
      }
      bool m_ = t < lb;
      float cold = cl[tid], hold = hloc[tid];
      float si = 1.f / (1.f + __expf(-gt[0])), sf = 1.f / (1.f + __expf(-gt[1]));
      float so = 1.f / (1.f + __expf(-gt[3]));
      float cn = sf * cold + si * tanhf(gt[2]);
      float hv = so * tanhf(cn);
      float cne = m_ ? cn : cold;
      float hne = m_ ? hv : hold;
      cl[tid] = cne; hloc[tid] = hne;
      st_coh_b16(&hnx[b * 512 + u0 + du], (__bf16)hne);
      obd[((size_t)b * SS + t) * 512 + u0 + du] = m_ ? (__bf16)hv : (__bf16)0.f;
      if (t + 1 < SS) {   // prefetch next xv; drains at the barrier
#pragma unroll
        for (int g = 0; g < 4; g++)
          xv[g] = xgd[((size_t)b * SS + t + 1) * 2048 + g * 512 + u0 + du];
      }
    }
    gbar(flags, t + 1, 256, bk);
  }
  if (tid < 128) {
    int b = tid >> 2, du = tid & 3;
    cenc[(size_t)dir * 16384 + b * 512 + u0 + du] = cl[tid];
  }
}

// ---------------------------------------------------------------- compose
__global__ void compose_kernel(const __bf16* __restrict__ ob, const __bf16* __restrict__ g_h,
                               const float* __restrict__ cenc, const int* __restrict__ lens,
                               __bf16* __restrict__ senc, __bf16* __restrict__ g_x0,
                               float* __restrict__ cdec) {
  int idx = blockIdx.x * 256 + threadIdx.x;
  const int N1 = 1536 * 1024;
  if (idx < N1) {
    int u = idx & 1023, bs = idx >> 10, b = bs / SS, s = bs - b * SS;
    __bf16 v;
    if (u < 512) v = ob[(size_t)bs * 512 + u];
    else {
      int len = lens[b];
      if (s < len) {
        int rs = len - 1 - s;
        v = ob[(size_t)(1536 * 512) + ((size_t)b * SS + rs) * 512 + (u - 512)];
      } else v = (__bf16)0.f;
    }
    senc[idx] = v;
  } else if (idx < N1 + 32 * 2048) {
    int k = idx - N1;
    int b = k >> 11, u = k & 2047;
    __bf16 v = (__bf16)0.f;
    if (u >= 1024) {
      int uu = u - 1024;
      v = (uu < 512) ? g_h[b * 512 + uu] : g_h[32768 + b * 512 + (uu - 512)];
    }
    g_x0[k] = v;
  } else if (idx < N1 + 32 * 2048 + 32 * 1024) {
    int k = idx - N1 - 32 * 2048;
    int b = k >> 10, u = k & 1023;
    cdec[k] = (u < 512) ? cenc[b * 512 + u] : cenc[16384 + b * 512 + (u - 512)];
  }
}

// ---------------------------------------------------------------- persistent decoder
// 128 blocks x 8 u-dims; per-timestep x buffers (first-touch). wa-half: plain reads
// (L2-shared). h-half: coh reads (burst + one wait). R2-verified sync structure.
__global__ __launch_bounds__(256) void dec_persistent(
    const __bf16* __restrict__ Wd,     // [4096][2048] bf16
    const float* __restrict__ pre,     // [1536][4096]
    const __bf16* __restrict__ senc,   // [32][48][1024] bf16 (rows >= len are ZERO)
    const __bf16* __restrict__ sencT,  // [32][1024][48] bf16
    const int* __restrict__ lens,
    const float* __restrict__ cdec,    // [32][1024]
    __bf16* __restrict__ xbuf,         // [49][32][2048] bf16 (slot0 = wa0|h0)
    __bf16* __restrict__ outs,         // [1536][2048] bf16
    int* __restrict__ flags) {
  const int bk = blockIdx.x;           // 128 blocks
  const int u0 = bk * 8;
  const int tid = threadIdx.x, lane = tid & 63, wave = tid >> 6;
  __shared__ __bf16 Wl[32 * 2056];
  __shared__ float gsc[4 * 1024];
  __shared__ float cl[256];
  __shared__ float asm_l[48];
  {
    int row = tid >> 3, t8 = tid & 7;
    int g = row >> 3, du = row & 7;
    const __bf16* src = Wd + (size_t)(g * 1024 + u0 + du) * 2048;
    for (int c = t8 * 256, e = t8 * 256 + 256; c < e; c += 8)
      *(bf16x8*)&Wl[row * 2056 + c] = *(const bf16x8*)&src[c];
  }
  cl[tid] = cdec[(size_t)(tid >> 3) * 1024 + u0 + (tid & 7)];
  __syncthreads();
  const int nr = lane & 15, q8 = (lane >> 4) * 8;
  const int bC = bk >> 2, j0 = (bk & 3) * 256;
  const int lenC = lens[bC];
  const int b_ = tid >> 3, du_ = tid & 7;
  float xv[4];
#pragma unroll
  for (int g = 0; g < 4; g++)
    xv[g] = pre[((size_t)b_ * TT) * 4096 + g * 1024 + u0 + du_];
  for (int t = 0; t < TT; t++) {
    const __bf16* xc = xbuf + (size_t)t * 65536;
    __bf16* xn = xbuf + (size_t)(t + 1) * 65536;
    f32x4 acc00 = {0.f,0.f,0.f,0.f}, acc01 = {0.f,0.f,0.f,0.f};
    f32x4 acc10 = {0.f,0.f,0.f,0.f}, acc11 = {0.f,0.f,0.f,0.f};
    const int kb = wave * 512;
    bf16x8 a0[16], a1[16];
    if (wave < 2) {                       // k<1024: wa region, plain (L2-shared)
#pragma unroll
      for (int ks = 0; ks < 16; ks++) {
        int k0 = kb + ks * 32;
        a0[ks] = *(const bf16x8*)&xc[nr * 2048 + k0 + q8];
        a1[ks] = *(const bf16x8*)&xc[(nr + 16) * 2048 + k0 + q8];
      }
    } else {                              // k>=1024: h region, multi-writer lines
#pragma unroll
      for (int ks = 0; ks < 16; ks++) {
        int k0 = kb + ks * 32;
        a0[ks] = ld_coh_x8(&xc[nr * 2048 + k0 + q8]);
        a1[ks] = ld_coh_x8(&xc[(nr + 16) * 2048 + k0 + q8]);
      }
      asm volatile("s_waitcnt vmcnt(0)" ::: "memory");
      __builtin_amdgcn_sched_barrier(0);
    }
#pragma unroll
    for (int ks = 0; ks < 16; ks++) {
      int k0 = kb + ks * 32;
      bf16x8 b0 = *(const bf16x8*)&Wl[nr * 2056 + k0 + q8];
      bf16x8 b1 = *(const bf16x8*)&Wl[(nr + 16) * 2056 + k0 + q8];
      acc00 = __builtin_amdgcn_mfma_f32_16x16x32_bf16(a0[ks], b0, acc00, 0, 0, 0);
      acc01 = __builtin_amdgcn_mfma_f32_16x16x32_bf16(a0[ks], b1, acc01, 0, 0, 0);
      acc10 = __builtin_amdgcn_mfma_f32_16x16x32_bf16(a1[ks], b0, acc10, 0, 0, 0);
      acc11 = __builtin_amdgcn_mfma_f32_16x16x32_bf16(a1[ks], b1, acc11, 0, 0, 0);
    }
#pragma unroll
    for (int rg = 0; rg < 4; rg++) {
      int m = (lane >> 4) * 4 + rg;
      gsc[wave * 1024 + m * 32 + nr]             = acc00[rg];
      gsc[wave * 1024 + m * 32 + 16 + nr]        = acc01[rg];
      gsc[wave * 1024 + (16 + m) * 32 + nr]      = acc10[rg];
      gsc[wave * 1024 + (16 + m) * 32 + 16 + nr] = acc11[rg];
    }
    __syncthreads();
    {
      float gt[4];
#pragma unroll
      for (int g = 0; g < 4; g++) {
        int base = b_ * 32 + g * 8 + du_;
        gt[g] = xv[g] + gsc[base] + gsc[1024 + base] + gsc[2048 + base] + gsc[3072 + base];
      }
      float cold = cl[tid];
      float si = 1.f / (1.f + __expf(-gt[0])), sf = 1.f / (1.f + __expf(-gt[1]));
      float so = 1.f / (1.f + __expf(-gt[3]));
      float cn = sf * cold + si * tanhf(gt[2]);
      float hv = so * tanhf(cn);
      cl[tid] = cn;
      __bf16 hb = (__bf16)hv;
      st_coh_b16(&xn[b_ * 2048 + 1024 + u0 + du_], hb);          // cross-block
      outs[((size_t)b_ * TT + t) * 2048 + 1024 + u0 + du_] = hb; // post-kernel
    }
    if (t + 1 < TT) {   // next pre-slice; drains at gbar1
#pragma unroll
      for (int g = 0; g < 4; g++)
        xv[g] = pre[((size_t)b_ * TT + t + 1) * 4096 + g * 1024 + u0 + du_];
    }
    gbar(flags, 2 * t + 1, 128, bk);   // h(t) visible everywhere
    // ---- attention: 4 blocks redundantly compute align+softmax for their bC
    {
      const __bf16* hh = xn + bC * 2048 + 1024;
      bf16x8 h0 = ld_coh_x8(&hh[lane * 16]);     // multi-writer lines -> coherent
      bf16x8 h1 = ld_coh_x8(&hh[lane * 16 + 8]);
      asm volatile("s_waitcnt vmcnt(0)" ::: "memory");
      __builtin_amdgcn_sched_barrier(0);
      float hf[16];
#pragma unroll
      for (int i = 0; i < 8; i++) { hf[i] = (float)h0[i]; hf[8 + i] = (float)h1[i]; }
      // unconditional dots (senc rows >= len are zero) -> fully pipelined loads,
      // then 12 independent 6-level shuffle chains batched per level
      float ps[12];
      const __bf16* seb = senc + (size_t)bC * SS * 1024;
#pragma unroll
      for (int si = 0; si < 12; si++) {
        int s = wave * 12 + si;
        const __bf16* se = seb + (size_t)s * 1024;
        bf16x8 s0 = *(const bf16x8*)&se[lane * 16];
        bf16x8 s1 = *(const bf16x8*)&se[lane * 16 + 8];
        float p = 0.f;
#pragma unroll
        for (int i = 0; i < 8; i++) p += (float)s0[i] * hf[i] + (float)s1[i] * hf[8 + i];
        ps[si] = p;
      }
#pragma unroll
      for (int off = 32; off > 0; off >>= 1) {
#pragma unroll
        for (int si = 0; si < 12; si++) ps[si] += __shfl_xor(ps[si], off, 64);
      }
      if (lane == 0) {
#pragma unroll
        for (int si = 0; si < 12; si++) {
          int s = wave * 12 + si;
          asm_l[s] = (s < lenC) ? ps[si] : -1e30f;
        }
      }
      __syncthreads();
      if (wave == 0) {
        float a = (lane < SS) ? asm_l[lane] : -1e30f;
        float mx = a;
#pragma unroll
        for (int off = 32; off > 0; off >>= 1) mx = fmaxf(mx, __shfl_xor(mx, off, 64));
        float p = (lane < SS) ? __expf(a - mx) : 0.f;
        float sm = p;
#pragma unroll
        for (int off = 32; off > 0; off >>= 1) sm += __shfl_xor(sm, off, 64);
        if (lane < SS) asm_l[lane] = p / sm;
      }
      __syncthreads();
      {
        int j = j0 + tid;
        const __bf16* srow = sencT + ((size_t)bC * 1024 + j) * 48;  // contiguous 48
        bf16x8 v0 = *(const bf16x8*)&srow[0];
        bf16x8 v1 = *(const bf16x8*)&srow[8];
        bf16x8 v2 = *(const bf16x8*)&srow[16];
        bf16x8 v3 = *(const bf16x8*)&srow[24];
        bf16x8 v4 = *(const bf16x8*)&srow[32];
        bf16x8 v5 = *(const bf16x8*)&srow[40];
        float w = 0.f;
#pragma unroll
        for (int i = 0; i < 8; i++) {
          w += asm_l[i]      * (float)v0[i];
          w += asm_l[8 + i]  * (float)v1[i];
          w += asm_l[16 + i] * (float)v2[i];
          w += asm_l[24 + i] * (float)v3[i];
          w += asm_l[32 + i] * (float)v4[i];
          w += asm_l[40 + i] * (float)v5[i];
        }
        __bf16 wb = (__bf16)w;
        st_coh_b16(&xn[bC * 2048 + j], wb);             // single-writer lines
        outs[((size_t)bC * TT + t) * 2048 + j] = wb;    // post-kernel
      }
    }
    gbar(flags, 2 * t + 2, 128, bk);   // wa(t) visible everywhere
  }
}

// ---------------------------------------------------------------- target logit per row
__global__ __launch_bounds__(256) void tgt_logit_kernel(
    const __bf16* __restrict__ outs_bf, const float* __restrict__ WsW,
    const float* __restrict__ Wsb, const int* __restrict__ tgt_tokens,
    float* __restrict__ tlogit) {
  const int r = blockIdx.x;
  const int b = r / TT, t = r % TT;
  const int tgt = tgt_tokens[b * (TT + 1) + t + 1];
  const __bf16* a = outs_bf + (size_t)r * 2048;
  const float* w = WsW + (size_t)tgt * 2048;
  const int tid = threadIdx.x;
  float p = 0;
  for (int k = tid; k < 2048; k += 256) p += (float)a[k] * w[k];
  for (int off = 32; off > 0; off >>= 1) p += __shfl_down(p, off, 64);
  __shared__ float red[4];
  if ((tid & 63) == 0) red[tid >> 6] = p;
  __syncthreads();
  if (tid == 0) tlogit[r] = red[0] + red[1] + red[2] + red[3] + Wsb[tgt];
}

// ---------------------------------------------------------------- final reduce
__global__ void final_kernel(const float* __restrict__ rowsum, const float* __restrict__ tlogit,
                             const int* __restrict__ tgt_tokens, float* __restrict__ out) {
  const int tid = threadIdx.x;
  float s = 0;
  for (int r = tid; r < BB * TT; r += 256) {
    int b = r / TT, t = r % TT;
    int tgt = tgt_tokens[b * (TT + 1) + t + 1];
    if (tgt != 0) s += logf(rowsum[r]) - tlogit[r];
  }
  for (int off = 32; off > 0; off >>= 1) s += __shfl_down(s, off, 64);
  __shared__ float red[4];
  if ((tid & 63) == 0) red[tid >> 6] = s;
  __syncthreads();
  if (tid == 0) out[0] = red[0] + red[1] + red[2] + red[3];
}

// ================================================================ host
extern "C" void kernel_launch(void* const* d_in, const int* in_sizes, int n_in,
                              void* d_out, int out_size, void* d_ws, size_t ws_size,
                              hipStream_t stream) {
  const float* enc_embed = (const float*)d_in[0];
  const float* dec_embed = (const float*)d_in[1];
  const float* eWih_f = (const float*)d_in[2];
  const float* eWhh_f = (const float*)d_in[3];
  const float* ebih_f = (const float*)d_in[4];
  const float* ebhh_f = (const float*)d_in[5];
  const float* eWih_b = (const float*)d_in[6];
  const float* eWhh_b = (const float*)d_in[7];
  const float* ebih_b = (const float*)d_in[8];
  const float* ebhh_b = (const float*)d_in[9];
  const float* dWih = (const float*)d_in[10];
  const float* dWhh = (const float*)d_in[11];
  const float* dbih = (const float*)d_in[12];
  const float* dbhh = (const float*)d_in[13];
  const float* WsW  = (const float*)d_in[14];
  const float* Wsb  = (const float*)d_in[15];
  const int* src_tokens  = (const int*)d_in[16];
  const int* src_lengths = (const int*)d_in[17];
  const int* tgt_tokens  = (const int*)d_in[18];
  float* W = (float*)d_ws;

  size_t o = 0;
  auto alloc = [&](size_t n) { size_t r = o; o += (n + 63) & ~(size_t)63; return r; };
  // ---- zeroed region
  const size_t flagsE = alloc(256 * 16);
  const size_t flagsD = alloc(256 * 16);
  const size_t ghenc = alloc(32768);                   // 2dir*2buf*32*512 bf16
  const size_t rsum  = alloc(BB * TT);
  const size_t zbytes = o * sizeof(float);
  // ---- rest
  const size_t cenc  = alloc(2 * BB * 512);
  const size_t cdec  = alloc(BB * 1024);
  const size_t tlog  = alloc(BB * TT);
  const size_t xg    = alloc((size_t)2 * 1536 * 2048);
  const size_t pre   = alloc((size_t)1536 * 4096);
  const size_t obuf  = alloc((size_t)2 * 1536 * 512 / 2);   // bf16
  const size_t senc  = alloc((size_t)1536 * 1024 / 2);      // bf16
  const size_t sencT = alloc((size_t)32 * 1024 * 48 / 2);   // bf16 transposed
  const size_t gx    = alloc((size_t)49 * 32 * 2048 / 2);   // bf16, 49 per-t slots
  const size_t wdec  = alloc((size_t)4096 * 2048 / 2);      // bf16
  const size_t wenc  = alloc((size_t)2 * 2048 * 512 / 2);   // bf16
  const size_t embbf = alloc(786432 / 2);
  const size_t embRbf= alloc(786432 / 2);
  const size_t dembbf= alloc(786432 / 2);
  const size_t wihfbf= alloc(1048576 / 2);
  const size_t wihbbf= alloc(1048576 / 2);
  const size_t dwihebf = alloc((size_t)4096 * 512 / 2);
  const size_t outsbf  = alloc((size_t)1536 * 2048 / 2);
  const size_t wsbf    = alloc((size_t)VV * 2048 / 2);      // bf16 Ws_W (131 MB)
  const bool wsbf_fit  = (o * sizeof(float)) <= ws_size;

  (void)hipMemsetAsync(W, 0, zbytes, stream);

  embed_src_kernel<<<3072, 256, 0, stream>>>(enc_embed, src_tokens, src_lengths,
                                             (__bf16*)(W + embbf), (__bf16*)(W + embRbf));
  embed_tgt_kernel<<<3072, 256, 0, stream>>>(dec_embed, tgt_tokens, (__bf16*)(W + dembbf));
  f2bf_kernel<<<1024, 256, 0, stream>>>(eWih_f, (__bf16*)(W + wihfbf), 262144);
  f2bf_kernel<<<1024, 256, 0, stream>>>(eWih_b, (__bf16*)(W + wihbbf), 262144);
  f2bf_kernel<<<1024, 256, 0, stream>>>(eWhh_f, (__bf16*)(W + wenc), 262144);
  f2bf_kernel<<<1024, 256, 0, stream>>>(eWhh_b, (__bf16*)(W + wenc) + 1048576, 262144);
  f2bf_slice_kernel<<<8192, 256, 0, stream>>>(dWih, (__bf16*)(W + dwihebf), 4096, 512, 1536, 1024);
  wdec_build_kernel<<<32768, 256, 0, stream>>>(dWih, dWhh, (__bf16*)(W + wdec));
  if (wsbf_fit)
    f2bf_kernel<<<64000, 256, 0, stream>>>(WsW, (__bf16*)(W + wsbf), VV * 2048 / 4);

  gemm_bf16_kernel<<<dim3(12, 16), 256, 0, stream>>>((__bf16*)(W + embbf), (__bf16*)(W + wihfbf),
                                                     ebih_f, ebhh_f, W + xg, 512, 2048);
  gemm_bf16_kernel<<<dim3(12, 16), 256, 0, stream>>>((__bf16*)(W + embRbf), (__bf16*)(W + wihbbf),
                                                     ebih_b, ebhh_b, W + xg + (size_t)1536 * 2048, 512, 2048);
  gemm_bf16_kernel<<<dim3(12, 32), 256, 0, stream>>>((__bf16*)(W + dembbf), (__bf16*)(W + dwihebf),
                                                     dbih, dbhh, W + pre, 512, 4096);

  enc_persistent<<<256, 256, 0, stream>>>((__bf16*)(W + wenc), W + xg, src_lengths,
                                          (__bf16*)(W + ghenc), W + cenc,
                                          (__bf16*)(W + obuf), (int*)(W + flagsE));
  compose_kernel<<<6528, 256, 0, stream>>>((__bf16*)(W + obuf), (__bf16*)(W + ghenc),
                                           W + cenc, src_lengths,
                                           (__bf16*)(W + senc), (__bf16*)(W + gx), W + cdec);
  sencT_build<<<512, 256, 0, stream>>>((const __bf16*)(W + senc), (__bf16*)(W + sencT));
  dec_persistent<<<128, 256, 0, stream>>>((__bf16*)(W + wdec), W + pre, (__bf16*)(W + senc),
                                          (const __bf16*)(W + sencT),
                                          src_lengths, W + cdec, (__bf16*)(W + gx),
                                          (__bf16*)(W + outsbf), (int*)(W + flagsD));

  if (wsbf_fit)
    logits_kernel<1><<<dim3(12, 250), 256, 0, stream>>>((const __bf16*)(W + outsbf),
                                                        (const void*)(W + wsbf), Wsb, W + rsum);
  else
    logits_kernel<0><<<dim3(12, 250), 256, 0, stream>>>((const __bf16*)(W + outsbf),
                                                        (const void*)WsW, Wsb, W + rsum);
  tgt_logit_kernel<<<1536, 256, 0, stream>>>((const __bf16*)(W + outsbf), WsW, Wsb, tgt_tokens, W + tlog);
  final_kernel<<<1, 256, 0, stream>>>(W + rsum, W + tlog, tgt_tokens, (float*)d_out);
}